// Round 7
// baseline (10271.524 us; speedup 1.0000x reference)
//
#include <hip/hip_runtime.h>
#include <stdint.h>

#define J_ 58
#define E_ 3306
#define B_ 32
#define NIN_ 192
#define H_ 512
#define NOUT_ 128
#define M_EDGE (B_*E_)   /* 105792 */
#define M_NODE (B_*J_)   /* 1856  */
#define NP_ 256          /* stats partial blocks */

typedef unsigned short u16;
typedef __attribute__((ext_vector_type(4))) unsigned int uint4v;

__device__ __forceinline__ float b2f(u16 u){ return __uint_as_float(((uint32_t)u)<<16); }
__device__ __forceinline__ u16 f2b(float f){
  uint32_t u = __float_as_uint(f);
  u += 0x7FFFu + ((u>>16)&1u);
  return (u16)(u>>16);
}

// ---------------- graph preprocessing (1 block) ----------------
__global__ __launch_bounds__(256) void build_graph(const int* __restrict__ ei,
    float* __restrict__ Adj, int* __restrict__ csroff, int* __restrict__ csredg)
{
  __shared__ float adj[J_][J_];
  __shared__ int   deg[J_];
  __shared__ float dinv[J_];
  __shared__ int   off[J_+1];
  __shared__ int   cur[J_];
  const int t = threadIdx.x;
  const int* srcI = ei;
  const int* dstI = ei + E_;
  for (int i = t; i < J_*J_; i += 256) adj[i/J_][i%J_] = 0.f;
  if (t < J_) { deg[t] = 0; cur[t] = 0; }
  __syncthreads();
  for (int e = t; e < E_; e += 256) {
    atomicAdd(&adj[dstI[e]][srcI[e]], 1.f);
    atomicAdd(&deg[dstI[e]], 1);
  }
  __syncthreads();
  if (t < J_) adj[t][t] += 1.f;
  __syncthreads();
  if (t < J_) {
    float s = 0.f;
    for (int j = 0; j < J_; ++j) s += adj[t][j];
    dinv[t] = rsqrtf(s);
  }
  __syncthreads();
  for (int i = t; i < J_*J_; i += 256) {
    int r = i / J_, c = i % J_;
    Adj[i] = dinv[r]*adj[r][c]*dinv[c];
  }
  if (t == 0) {
    off[0] = 0;
    for (int n = 0; n < J_; ++n) off[n+1] = off[n] + deg[n];
  }
  __syncthreads();
  if (t <= J_) csroff[t] = off[t];
  for (int e = t; e < E_; e += 256) {
    int d = dstI[e];
    int p = atomicAdd(&cur[d], 1);
    csredg[off[d] + p] = e;
  }
}

// -------- weight convert+transpose f32 [K,N] -> bf16 [N,K] --------
__global__ __launch_bounds__(256) void transpose_cv(const float* __restrict__ src,
    u16* __restrict__ dst, int K, int N)
{
  int idx = blockIdx.x*256 + threadIdx.x;
  if (idx >= K*N) return;
  int k = idx / N, n = idx - k*N;
  dst[(size_t)n*K + k] = f2b(src[idx]);
}

// ---------------- Ax = A @ x  (f32 x -> bf16 out) ----------------
__global__ __launch_bounds__(192) void ax_kernel(const float* __restrict__ Adj,
    const float* __restrict__ x, u16* __restrict__ Ax)
{
  int bi = blockIdx.x;            // b*J_ + i
  int b = bi / J_, i = bi - b*J_;
  __shared__ float Arow[J_];
  if (threadIdx.x < J_) Arow[threadIdx.x] = Adj[i*J_ + threadIdx.x];
  __syncthreads();
  int f = threadIdx.x;
  const float* xb = x + (size_t)b*J_*NIN_ + f;
  float acc = 0.f;
  for (int j = 0; j < J_; ++j) acc += Arow[j]*xb[(size_t)j*NIN_];
  Ax[(size_t)bi*NIN_ + f] = f2b(acc);
}

// ---------------- scalar GEMM: A[M,K] bf16, Bt[N,K] bf16; 16x16 tile/block ----
// MODE 0: outF = raw f32
// MODE 1: outB = bf16(relu(acc + bias[n]))        (bias f32)
// MODE 2: outB = bf16(relu(acc + g1[b,src,n] + g2[b,dst,n] + crow[n]))
// MODE 3: outF = f32(acc + crow[n])     <-- FINAL OUTPUT IS FLOAT32
template<int MODE>
__global__ __launch_bounds__(256) void sgemm(
    const u16* __restrict__ Aop, const u16* __restrict__ Bt,
    const int N, const int K,
    const float* __restrict__ bias,
    const float* __restrict__ g1, const float* __restrict__ g2,
    const float* __restrict__ crow,
    const int* __restrict__ srcI, const int* __restrict__ dstI,
    u16* __restrict__ outB, float* __restrict__ outF)
{
  const int tid = threadIdx.x;
  const int m = blockIdx.x*16 + (tid>>4);
  const int n = blockIdx.y*16 + (tid&15);
  const u16* ap = Aop + (size_t)m*K;
  const u16* bp = Bt  + (size_t)n*K;
  float acc = 0.f;
  for (int k = 0; k < K; k += 8) {
    uint4v av = *(const uint4v*)(ap + k);
    uint4v bv = *(const uint4v*)(bp + k);
#pragma unroll
    for (int j = 0; j < 4; ++j) {
      uint32_t pa = av[j], pb = bv[j];
      acc += __uint_as_float(pa<<16)           * __uint_as_float(pb<<16);
      acc += __uint_as_float(pa & 0xFFFF0000u) * __uint_as_float(pb & 0xFFFF0000u);
    }
  }
  if (MODE == 0) {
    outF[(size_t)m*N + n] = acc;
  } else if (MODE == 1) {
    outB[(size_t)m*N + n] = f2b(fmaxf(acc + bias[n], 0.f));
  } else if (MODE == 2) {
    uint32_t bb = (uint32_t)m / E_;
    uint32_t ke = (uint32_t)m - bb*E_;
    float v = acc + g1[((size_t)bb*J_ + srcI[ke])*H_ + n]
                  + g2[((size_t)bb*J_ + dstI[ke])*H_ + n]
                  + crow[n];
    outB[(size_t)m*N + n] = f2b(fmaxf(v, 0.f));
  } else { // MODE 3: f32 final output
    outF[(size_t)m*N + n] = acc + crow[n];
  }
}

// ---------------- edge assembly 1: e = relu(hs[src]+hd[dst]+b1) ----------------
__global__ __launch_bounds__(256) void edge1_kernel(const float* __restrict__ hs,
    const float* __restrict__ hd, const float* __restrict__ b1,
    const int* __restrict__ srcI, const int* __restrict__ dstI,
    u16* __restrict__ e_raw)
{
  const int t = threadIdx.x;
  const int row0 = blockIdx.x * 16;
  float bv0 = b1[t], bv1 = b1[t+256];
  for (int r = 0; r < 16; ++r) {
    int m = row0 + r;
    uint32_t bb = (uint32_t)m / E_;
    uint32_t ke = (uint32_t)m - bb*E_;
    const float* ps = hs + ((size_t)bb*J_ + srcI[ke])*H_;
    const float* pd = hd + ((size_t)bb*J_ + dstI[ke])*H_;
    float v0 = fmaxf(ps[t]     + pd[t]     + bv0, 0.f);
    float v1 = fmaxf(ps[t+256] + pd[t+256] + bv1, 0.f);
    e_raw[(size_t)m*H_ + t]       = f2b(v0);
    e_raw[(size_t)m*H_ + t + 256] = f2b(v1);
  }
}

// ---------------- deterministic BN stats: pass 1 (column scan, f64 partials) ----
// partial layout: [NP_][H_][2] (sum, sumsq)
__global__ __launch_bounds__(256) void stats_scan(const u16* __restrict__ e,
    double* __restrict__ partial)
{
  const int blk = blockIdx.x;   // 0..NP_-1
  const int t = threadIdx.x;
  double s0=0.0,q0=0.0,s1=0.0,q1=0.0;
  for (int m = blk; m < M_EDGE; m += NP_) {
    const u16* row = e + (size_t)m*H_;
    float v0 = b2f(row[t]);
    float v1 = b2f(row[t+256]);
    s0 += (double)v0; q0 += (double)v0*v0;
    s1 += (double)v1; q1 += (double)v1*v1;
  }
  double* p0 = partial + ((size_t)blk*H_ + t)*2;
  p0[0] = s0; p0[1] = q0;
  double* p1 = partial + ((size_t)blk*H_ + t + 256)*2;
  p1[0] = s1; p1[1] = q1;
}

// ---------------- BN finalize (f64, deterministic; g/b f32) ----------------
__global__ __launch_bounds__(512) void bn_fin(const double* __restrict__ partial,
    const float* __restrict__ g, const float* __restrict__ b,
    float* __restrict__ scale, float* __restrict__ shift)
{
  int c = threadIdx.x;
  double s = 0.0, q = 0.0;
  for (int k = 0; k < NP_; ++k) {
    const double* p = partial + ((size_t)k*H_ + c)*2;
    s += p[0]; q += p[1];
  }
  const double invM = 1.0 / (double)M_EDGE;
  double mu = s * invM;
  double var = q * invM - mu*mu;
  if (var < 0.0) var = 0.0;
  float sc = g[c] * (float)(1.0 / sqrt(var + 1e-5));
  scale[c] = sc;
  shift[c] = b[c] - (float)mu*sc;
}

// ---------------- BN apply in place: e = bf16(scale*e + shift) ----------------
// total elems = M_EDGE*H = 54,165,504 = 26448 blocks * 256 thr * 8 elems
__global__ __launch_bounds__(256) void bn_apply(u16* __restrict__ e,
    const float* __restrict__ scale, const float* __restrict__ shift)
{
  size_t gid = (size_t)blockIdx.x*256 + threadIdx.x;
  size_t i8 = gid*8;
  int c0 = (int)(i8 & 511);
  uint4v v = *(const uint4v*)(e + i8);
  uint4v o;
#pragma unroll
  for (int j = 0; j < 4; ++j) {
    float lo = __uint_as_float(v[j]<<16);
    float hi = __uint_as_float(v[j] & 0xFFFF0000u);
    int c = c0 + 2*j;
    u16 rlo = f2b(scale[c]*lo + shift[c]);
    u16 rhi = f2b(scale[c+1]*hi + shift[c+1]);
    o[j] = (uint32_t)rlo | ((uint32_t)rhi<<16);
  }
  *(uint4v*)(e + i8) = o;
}

// ---------------- scatter: node_raw[b,n,:] = sum_{k: dst=n} e_bn[b,k,:] ----------------
__global__ __launch_bounds__(256) void scatter_kernel(const u16* __restrict__ e_bn,
    const int* __restrict__ csroff, const int* __restrict__ csredg, float* __restrict__ node_raw)
{
  int bi = blockIdx.x;
  int b = bi / J_, n = bi - b*J_;
  int beg = csroff[n], end = csroff[n+1];
  int c0 = threadIdx.x, c1 = threadIdx.x + 256;
  float a0 = 0.f, a1 = 0.f;
  for (int p = beg; p < end; ++p) {
    const u16* er = e_bn + ((size_t)b*E_ + csredg[p])*H_;
    a0 += b2f(er[c0]); a1 += b2f(er[c1]);
  }
  node_raw[(size_t)bi*H_ + c0] = a0;
  node_raw[(size_t)bi*H_ + c1] = a1;
}

// ---------------- An = bf16(A @ node)  (plain, no fold) ----------------
__global__ __launch_bounds__(256) void an_kernel(const float* __restrict__ Adj,
    const float* __restrict__ node_raw, u16* __restrict__ An)
{
  int bi = blockIdx.x;
  int b = bi / J_, i = bi - b*J_;
  __shared__ float Arow[J_];
  if (threadIdx.x < J_) Arow[threadIdx.x] = Adj[i*J_ + threadIdx.x];
  __syncthreads();
#pragma unroll
  for (int h = 0; h < 2; ++h) {
    int c = threadIdx.x + h*256;
    const float* nb = node_raw + (size_t)b*J_*H_ + c;
    float acc = 0.f;
    for (int j = 0; j < J_; ++j) acc += Arow[j]*nb[(size_t)j*H_];
    An[(size_t)bi*H_ + c] = f2b(acc);
  }
}

// =====================================================================
extern "C" void kernel_launch(void* const* d_in, const int* in_sizes, int n_in,
                              void* d_out, int out_size, void* d_ws, size_t ws_size,
                              hipStream_t stream)
{
  const float* x    = (const float*)d_in[0];
  const int*   ei   = (const int*)d_in[1];
  const float* g1w  = (const float*)d_in[2];
  const float* g1b  = (const float*)d_in[3];
  const float* m1w  = (const float*)d_in[4];
  const float* m1b  = (const float*)d_in[5];
  const float* bn1g = (const float*)d_in[6];
  const float* bn1b = (const float*)d_in[7];
  const float* g2w  = (const float*)d_in[8];
  const float* g2b  = (const float*)d_in[9];
  const float* m2w  = (const float*)d_in[10];
  const float* m2b  = (const float*)d_in[11];
  const float* bn2g = (const float*)d_in[12];
  const float* bn2b = (const float*)d_in[13];
  const float* fcw  = (const float*)d_in[14];
  const float* fcb  = (const float*)d_in[15];

  char* wsp = (char*)d_ws;
  size_t off = 0;
  auto alloc = [&](size_t bytes) -> char* {
    char* p = wsp + off;
    off = (off + bytes + 255) & ~(size_t)255;
    return p;
  };
  float* Adj    = (float*)alloc(J_*J_*4);
  int*   csroff = (int*)alloc((J_+1)*4);
  int*   csredg = (int*)alloc(E_*4);
  float* scale1 = (float*)alloc(H_*4);
  float* shift1 = (float*)alloc(H_*4);
  float* scale2 = (float*)alloc(H_*4);
  float* shift2 = (float*)alloc(H_*4);
  double* partial = (double*)alloc((size_t)NP_*H_*2*8);   // 2 MB, reused BN1/BN2
  u16* g1T  = (u16*)alloc((size_t)H_*NIN_*2);
  u16* g2T  = (u16*)alloc((size_t)H_*H_*2);
  u16* W1aT = (u16*)alloc((size_t)H_*H_*2);
  u16* W1bT = (u16*)alloc((size_t)H_*H_*2);
  u16* W2aT = (u16*)alloc((size_t)H_*H_*2);
  u16* W2bT = (u16*)alloc((size_t)H_*H_*2);
  u16* WcT  = (u16*)alloc((size_t)H_*H_*2);
  u16* fcT  = (u16*)alloc((size_t)NOUT_*H_*2);
  u16* Ax   = (u16*)alloc((size_t)M_NODE*NIN_*2);
  u16* h    = (u16*)alloc((size_t)M_NODE*H_*2);
  float* hs = (float*)alloc((size_t)M_NODE*H_*4);
  float* hd = (float*)alloc((size_t)M_NODE*H_*4);
  float* node_raw = (float*)alloc((size_t)M_NODE*H_*4);
  u16* An   = (u16*)alloc((size_t)M_NODE*H_*2);
  u16* h2   = (u16*)alloc((size_t)M_NODE*H_*2);
  float* h2s = (float*)alloc((size_t)M_NODE*H_*4);
  float* h2d = (float*)alloc((size_t)M_NODE*H_*4);
  u16* e_raw = (u16*)alloc((size_t)M_EDGE*H_*2);   // becomes x_skip after bn_apply
  u16* e2    = (u16*)alloc((size_t)M_EDGE*H_*2);   // becomes bn2(e2) after bn_apply
  if (off > ws_size) return;   // diagnostic: out stays 0 -> absmax == max|ref| ~ 4.375

  const int* srcI = ei;
  const int* dstI = ei + E_;
  float* outF = (float*)d_out;   // OUTPUT IS FLOAT32 (reference output dtype)

  build_graph<<<1, 256, 0, stream>>>(ei, Adj, csroff, csredg);

  transpose_cv<<<(NIN_*H_+255)/256, 256, 0, stream>>>(g1w, g1T, NIN_, H_);
  transpose_cv<<<(H_*H_+255)/256, 256, 0, stream>>>(g2w, g2T, H_, H_);
  transpose_cv<<<(H_*H_+255)/256, 256, 0, stream>>>(m1w, W1aT, H_, H_);
  transpose_cv<<<(H_*H_+255)/256, 256, 0, stream>>>(m1w + (size_t)H_*H_, W1bT, H_, H_);
  transpose_cv<<<(H_*H_+255)/256, 256, 0, stream>>>(m2w, W2aT, H_, H_);
  transpose_cv<<<(H_*H_+255)/256, 256, 0, stream>>>(m2w + (size_t)H_*H_, W2bT, H_, H_);
  transpose_cv<<<(H_*H_+255)/256, 256, 0, stream>>>(m2w + (size_t)2*H_*H_, WcT, H_, H_);
  transpose_cv<<<(H_*NOUT_+255)/256, 256, 0, stream>>>(fcw, fcT, H_, NOUT_);

  ax_kernel<<<M_NODE, 192, 0, stream>>>(Adj, x, Ax);

  // h = relu(Ax @ gcn1_w + b)
  sgemm<1><<<dim3(M_NODE/16, H_/16), 256, 0, stream>>>(Ax, g1T, H_, NIN_,
      g1b, nullptr, nullptr, nullptr, nullptr, nullptr, h, nullptr);
  // hs = h @ W1a, hd = h @ W1b (f32)
  sgemm<0><<<dim3(M_NODE/16, H_/16), 256, 0, stream>>>(h, W1aT, H_, H_,
      nullptr, nullptr, nullptr, nullptr, nullptr, nullptr, nullptr, hs);
  sgemm<0><<<dim3(M_NODE/16, H_/16), 256, 0, stream>>>(h, W1bT, H_, H_,
      nullptr, nullptr, nullptr, nullptr, nullptr, nullptr, nullptr, hd);
  // e_raw = relu(hs[src] + hd[dst] + b1)
  edge1_kernel<<<M_EDGE/16, 256, 0, stream>>>(hs, hd, m1b, srcI, dstI, e_raw);
  // BN1: stats then apply IN PLACE -> e_raw becomes x_skip
  stats_scan<<<NP_, 256, 0, stream>>>(e_raw, partial);
  bn_fin<<<1, 512, 0, stream>>>(partial, bn1g, bn1b, scale1, shift1);
  bn_apply<<<26448, 256, 0, stream>>>(e_raw, scale1, shift1);
  // edge2node on post-BN values (exactly the reference's scatter)
  scatter_kernel<<<M_NODE, 256, 0, stream>>>(e_raw, csroff, csredg, node_raw);
  an_kernel<<<M_NODE, 256, 0, stream>>>(Adj, node_raw, An);
  // h2 = relu(An @ gcn2_w + b2)
  sgemm<1><<<dim3(M_NODE/16, H_/16), 256, 0, stream>>>(An, g2T, H_, H_,
      g2b, nullptr, nullptr, nullptr, nullptr, nullptr, h2, nullptr);
  sgemm<0><<<dim3(M_NODE/16, H_/16), 256, 0, stream>>>(h2, W2aT, H_, H_,
      nullptr, nullptr, nullptr, nullptr, nullptr, nullptr, nullptr, h2s);
  sgemm<0><<<dim3(M_NODE/16, H_/16), 256, 0, stream>>>(h2, W2bT, H_, H_,
      nullptr, nullptr, nullptr, nullptr, nullptr, nullptr, nullptr, h2d);
  // e2 = relu(x_skip @ Wc + h2s[src] + h2d[dst] + mlp2_b)
  sgemm<2><<<dim3(M_EDGE/16, H_/16), 256, 0, stream>>>(e_raw, WcT, H_, H_,
      nullptr, h2s, h2d, m2b, srcI, dstI, e2, nullptr);
  // BN2: stats then apply IN PLACE
  stats_scan<<<NP_, 256, 0, stream>>>(e2, partial);
  bn_fin<<<1, 512, 0, stream>>>(partial, bn2g, bn2b, scale2, shift2);
  bn_apply<<<26448, 256, 0, stream>>>(e2, scale2, shift2);
  // out = bn2(e2) @ fc_w + fc_b   (FLOAT32 output)
  sgemm<3><<<dim3(M_EDGE/16, NOUT_/16), 256, 0, stream>>>(e2, fcT, NOUT_, H_,
      nullptr, nullptr, nullptr, fcb, nullptr, nullptr, nullptr, outF);
}

// Round 9
// 753.999 us; speedup vs baseline: 13.6227x; 13.6227x over previous
//
#include <hip/hip_runtime.h>
#include <stdint.h>

#define J_ 58
#define E_ 3306
#define B_ 32
#define NIN_ 192
#define H_ 512
#define NOUT_ 128
#define M_EDGE (B_*E_)   /* 105792 */
#define M_NODE (B_*J_)   /* 1856  */
#define NP_ 256          /* stats partial blocks */

typedef unsigned short u16;
typedef __attribute__((ext_vector_type(8))) short short8v;
typedef __attribute__((ext_vector_type(4))) float f32x4;
typedef __attribute__((ext_vector_type(4))) unsigned int uint4v;

__device__ __forceinline__ float b2f(u16 u){ return __uint_as_float(((uint32_t)u)<<16); }
__device__ __forceinline__ u16 f2b(float f){
  uint32_t u = __float_as_uint(f);
  u += 0x7FFFu + ((u>>16)&1u);
  return (u16)(u>>16);
}

// ---------------- graph preprocessing (1 block) ----------------
__global__ __launch_bounds__(256) void build_graph(const int* __restrict__ ei,
    float* __restrict__ Adj, float* __restrict__ aind,
    int* __restrict__ csroff, int* __restrict__ csredg)
{
  __shared__ float adj[J_][J_];
  __shared__ int   deg[J_];
  __shared__ float dinv[J_];
  __shared__ int   off[J_+1];
  __shared__ int   cur[J_];
  const int t = threadIdx.x;
  const int* srcI = ei;
  const int* dstI = ei + E_;
  for (int i = t; i < J_*J_; i += 256) adj[i/J_][i%J_] = 0.f;
  if (t < J_) { deg[t] = 0; cur[t] = 0; }
  __syncthreads();
  for (int e = t; e < E_; e += 256) {
    atomicAdd(&adj[dstI[e]][srcI[e]], 1.f);
    atomicAdd(&deg[dstI[e]], 1);
  }
  __syncthreads();
  if (t < J_) adj[t][t] += 1.f;
  __syncthreads();
  if (t < J_) {
    float s = 0.f;
    for (int j = 0; j < J_; ++j) s += adj[t][j];
    dinv[t] = rsqrtf(s);
  }
  __syncthreads();
  for (int i = t; i < J_*J_; i += 256) {
    int r = i / J_, c = i % J_;
    Adj[i] = dinv[r]*adj[r][c]*dinv[c];
  }
  if (t < J_) {
    float s = 0.f;
    for (int j = 0; j < J_; ++j) s += dinv[t]*adj[t][j]*dinv[j]*(float)deg[j];
    aind[t] = s;
  }
  if (t == 0) {
    off[0] = 0;
    for (int n = 0; n < J_; ++n) off[n+1] = off[n] + deg[n];
  }
  __syncthreads();
  if (t <= J_) csroff[t] = off[t];
  for (int e = t; e < E_; e += 256) {
    int d = dstI[e];
    int p = atomicAdd(&cur[d], 1);
    csredg[off[d] + p] = e;
  }
}

// -------- weight convert+transpose f32 [K,N] -> bf16 [N,K] --------
__global__ __launch_bounds__(256) void transpose_cv(const float* __restrict__ src,
    u16* __restrict__ dst, int K, int N)
{
  int idx = blockIdx.x*256 + threadIdx.x;
  if (idx >= K*N) return;
  int k = idx / N, n = idx - k*N;
  dst[(size_t)n*K + k] = f2b(src[idx]);
}

// ---------------- Ax = A @ x  (f32 x -> bf16 out) ----------------
__global__ __launch_bounds__(192) void ax_kernel(const float* __restrict__ Adj,
    const float* __restrict__ x, u16* __restrict__ Ax)
{
  int bi = blockIdx.x;            // b*J_ + i
  int b = bi / J_, i = bi - b*J_;
  __shared__ float Arow[J_];
  if (threadIdx.x < J_) Arow[threadIdx.x] = Adj[i*J_ + threadIdx.x];
  __syncthreads();
  int f = threadIdx.x;
  const float* xb = x + (size_t)b*J_*NIN_ + f;
  float acc = 0.f;
  for (int j = 0; j < J_; ++j) acc += Arow[j]*xb[(size_t)j*NIN_];
  Ax[(size_t)bi*NIN_ + f] = f2b(acc);
}

// ---------------- 64x64 MFMA GEMM (reg-staged LDS), 4 waves, BK=32 ----------------
// A [M,K] bf16 row-major, Bt [N,K] bf16 row-major.
// MODE 0: outF = raw f32
// MODE 1: outB = bf16(relu(acc + bias[n]))                (bias f32)
// MODE 2: outB = bf16(relu(acc + g1[b,src,n] + g2[b,dst,n] + crow[n]))
// MODE 3: outF = f32(acc + crow[n])                       (final output)
template<int MODE>
__global__ __launch_bounds__(256) void gemm64(
    const u16* __restrict__ Aop, const u16* __restrict__ Bt,
    const int M, const int N, const int K,
    const float* __restrict__ bias,
    const float* __restrict__ g1, const float* __restrict__ g2,
    const float* __restrict__ crow,
    const int* __restrict__ srcI, const int* __restrict__ dstI,
    u16* __restrict__ outB, float* __restrict__ outF)
{
  __shared__ __align__(16) u16 Al[64*32];
  __shared__ __align__(16) u16 Bl[64*32];
  const int tid = threadIdx.x;
  const int w = tid >> 6, l = tid & 63;
  const int row0 = blockIdx.x * 64, col0 = blockIdx.y * 64;
  f32x4 acc[4] = {};
  const u16* ag = Aop + (size_t)(row0 + (tid>>2))*K + (tid&3)*8;
  const u16* bg = Bt  + (size_t)(col0 + (tid>>2))*K + (tid&3)*8;
  const int fr = l & 15, fg = l >> 4;
  const int nk = K >> 5;
  for (int kt = 0; kt < nk; ++kt) {
    short8v av = *(const short8v*)ag;
    short8v bv = *(const short8v*)bg;
    ag += 32; bg += 32;
    __syncthreads();                 // prior tile consumed
    *(short8v*)(Al + tid*8) = av;    // row=tid>>2, k=(tid&3)*8
    *(short8v*)(Bl + tid*8) = bv;
    __syncthreads();                 // tile visible
    short8v a = *(const short8v*)(Al + (w*16 + fr)*32 + fg*8);
#pragma unroll
    for (int nt = 0; nt < 4; ++nt) {
      short8v b = *(const short8v*)(Bl + (nt*16 + fr)*32 + fg*8);
      acc[nt] = __builtin_amdgcn_mfma_f32_16x16x32_bf16(a, b, acc[nt], 0, 0, 0);
    }
  }
  if (MODE == 0) {
#pragma unroll
    for (int nt = 0; nt < 4; ++nt) {
      int gc = col0 + nt*16 + fr;
#pragma unroll
      for (int r = 0; r < 4; ++r) {
        int gr = row0 + w*16 + fg*4 + r;
        outF[(size_t)gr*N + gc] = acc[nt][r];
      }
    }
  } else if (MODE == 1) {
#pragma unroll
    for (int nt = 0; nt < 4; ++nt) {
      int gc = col0 + nt*16 + fr;
      float bv = bias[gc];
#pragma unroll
      for (int r = 0; r < 4; ++r) {
        int gr = row0 + w*16 + fg*4 + r;
        outB[(size_t)gr*N + gc] = f2b(fmaxf(acc[nt][r] + bv, 0.f));
      }
    }
  } else if (MODE == 2) {
    int mrow[4];
    const float* p1[4];
    const float* p2[4];
#pragma unroll
    for (int r = 0; r < 4; ++r) {
      int m = row0 + w*16 + fg*4 + r;
      mrow[r] = m;
      uint32_t bb = (uint32_t)m / E_;
      uint32_t ke = (uint32_t)m - bb*E_;
      p1[r] = g1 + ((size_t)bb*J_ + srcI[ke])*H_;
      p2[r] = g2 + ((size_t)bb*J_ + dstI[ke])*H_;
    }
#pragma unroll
    for (int nt = 0; nt < 4; ++nt) {
      int gc = col0 + nt*16 + fr;
      float cr = crow[gc];
#pragma unroll
      for (int r = 0; r < 4; ++r) {
        float v = acc[nt][r] + p1[r][gc] + p2[r][gc] + cr;
        outB[(size_t)mrow[r]*N + gc] = f2b(fmaxf(v, 0.f));
      }
    }
  } else { // MODE 3: f32 final output
#pragma unroll
    for (int nt = 0; nt < 4; ++nt) {
      int gc = col0 + nt*16 + fr;
      float cr = crow[gc];
#pragma unroll
      for (int r = 0; r < 4; ++r) {
        int gr = row0 + w*16 + fg*4 + r;
        outF[(size_t)gr*N + gc] = acc[nt][r] + cr;
      }
    }
  }
}

// ---------------- edge assembly 1: e = relu(hs[src]+hd[dst]+b1) ----------------
__global__ __launch_bounds__(256) void edge1_kernel(const float* __restrict__ hs,
    const float* __restrict__ hd, const float* __restrict__ b1,
    const int* __restrict__ srcI, const int* __restrict__ dstI,
    u16* __restrict__ e_raw)
{
  const int t = threadIdx.x;
  const int row0 = blockIdx.x * 16;
  float bv0 = b1[t], bv1 = b1[t+256];
  for (int r = 0; r < 16; ++r) {
    int m = row0 + r;
    uint32_t bb = (uint32_t)m / E_;
    uint32_t ke = (uint32_t)m - bb*E_;
    const float* ps = hs + ((size_t)bb*J_ + srcI[ke])*H_;
    const float* pd = hd + ((size_t)bb*J_ + dstI[ke])*H_;
    float v0 = fmaxf(ps[t]     + pd[t]     + bv0, 0.f);
    float v1 = fmaxf(ps[t+256] + pd[t+256] + bv1, 0.f);
    e_raw[(size_t)m*H_ + t]       = f2b(v0);
    e_raw[(size_t)m*H_ + t + 256] = f2b(v1);
  }
}

// ---------------- deterministic BN stats: pass 1 (column scan, f64 partials) ----
__global__ __launch_bounds__(256) void stats_scan(const u16* __restrict__ e,
    double* __restrict__ partial)
{
  const int blk = blockIdx.x;   // 0..NP_-1
  const int t = threadIdx.x;
  double s0=0.0,q0=0.0,s1=0.0,q1=0.0;
  for (int m = blk; m < M_EDGE; m += NP_) {
    const u16* row = e + (size_t)m*H_;
    float v0 = b2f(row[t]);
    float v1 = b2f(row[t+256]);
    s0 += (double)v0; q0 += (double)v0*v0;
    s1 += (double)v1; q1 += (double)v1*v1;
  }
  double* p0 = partial + ((size_t)blk*H_ + t)*2;
  p0[0] = s0; p0[1] = q0;
  double* p1 = partial + ((size_t)blk*H_ + t + 256)*2;
  p1[0] = s1; p1[1] = q1;
}

// ---------------- BN finalize (f64, deterministic; g/b f32) ----------------
__global__ __launch_bounds__(512) void bn_fin(const double* __restrict__ partial,
    const float* __restrict__ g, const float* __restrict__ b,
    float* __restrict__ scale, float* __restrict__ shift)
{
  int c = threadIdx.x;
  double s = 0.0, q = 0.0;
  for (int k = 0; k < NP_; ++k) {
    const double* p = partial + ((size_t)k*H_ + c)*2;
    s += p[0]; q += p[1];
  }
  const double invM = 1.0 / (double)M_EDGE;
  double mu = s * invM;
  double var = q * invM - mu*mu;
  if (var < 0.0) var = 0.0;
  float sc = g[c] * (float)(1.0 / sqrt(var + 1e-5));
  scale[c] = sc;
  shift[c] = b[c] - (float)mu*sc;
}

// ------- build scaled WcT bf16 [512,512] + crow1 (incl mlp2_b); m2w f32 -------
__global__ __launch_bounds__(256) void build_wc(const float* __restrict__ m2w,
    const float* __restrict__ m2b, const float* __restrict__ scale1, const float* __restrict__ shift1,
    u16* __restrict__ WcT, float* __restrict__ crow)
{
  int n = blockIdx.x;
  int t = threadIdx.x;
  __shared__ float red[256];
  float part = 0.f;
  for (int k = t; k < H_; k += 256) {
    float wv = m2w[(size_t)(2*H_ + k)*H_ + n];
    WcT[(size_t)n*H_ + k] = f2b(scale1[k]*wv);
    part += shift1[k]*wv;
  }
  red[t] = part; __syncthreads();
  for (int s = 128; s; s >>= 1) { if (t < s) red[t] += red[t+s]; __syncthreads(); }
  if (t == 0) crow[n] = red[0] + m2b[n];
}

// ------- build scaled fcT bf16 [128,512] + cvec (incl fc_b); fcw f32 -------
__global__ __launch_bounds__(256) void build_fc(const float* __restrict__ fcw,
    const float* __restrict__ fcb, const float* __restrict__ scale2, const float* __restrict__ shift2,
    u16* __restrict__ fcT, float* __restrict__ cvec)
{
  int n = blockIdx.x;
  int t = threadIdx.x;
  __shared__ float red[256];
  float part = 0.f;
  for (int k = t; k < H_; k += 256) {
    float wv = fcw[(size_t)k*NOUT_ + n];
    fcT[(size_t)n*H_ + k] = f2b(scale2[k]*wv);
    part += shift2[k]*wv;
  }
  red[t] = part; __syncthreads();
  for (int s = 128; s; s >>= 1) { if (t < s) red[t] += red[t+s]; __syncthreads(); }
  if (t == 0) cvec[n] = red[0] + fcb[n];
}

// ---------------- scatter: node_raw[b,n,:] = sum_{k: dst=n} e_raw[b,k,:] (PRE-BN) ----
__global__ __launch_bounds__(256) void scatter_kernel(const u16* __restrict__ e_raw,
    const int* __restrict__ csroff, const int* __restrict__ csredg, float* __restrict__ node_raw)
{
  int bi = blockIdx.x;
  int b = bi / J_, n = bi - b*J_;
  int beg = csroff[n], end = csroff[n+1];
  int c0 = threadIdx.x, c1 = threadIdx.x + 256;
  float a0 = 0.f, a1 = 0.f;
  for (int p = beg; p < end; ++p) {
    const u16* er = e_raw + ((size_t)b*E_ + csredg[p])*H_;
    a0 += b2f(er[c0]); a1 += b2f(er[c1]);
  }
  node_raw[(size_t)bi*H_ + c0] = a0;
  node_raw[(size_t)bi*H_ + c1] = a1;
}

// ------- An = bf16(scale1*(A @ node_raw) + shift1*aind[i])  (BN1 fold) -------
__global__ __launch_bounds__(256) void an_kernel(const float* __restrict__ Adj,
    const float* __restrict__ node_raw, const float* __restrict__ scale1,
    const float* __restrict__ shift1, const float* __restrict__ aind, u16* __restrict__ An)
{
  int bi = blockIdx.x;
  int b = bi / J_, i = bi - b*J_;
  __shared__ float Arow[J_];
  if (threadIdx.x < J_) Arow[threadIdx.x] = Adj[i*J_ + threadIdx.x];
  __syncthreads();
  float ai = aind[i];
#pragma unroll
  for (int h = 0; h < 2; ++h) {
    int c = threadIdx.x + h*256;
    const float* nb = node_raw + (size_t)b*J_*H_ + c;
    float acc = 0.f;
    for (int j = 0; j < J_; ++j) acc += Arow[j]*nb[(size_t)j*H_];
    An[(size_t)bi*H_ + c] = f2b(scale1[c]*acc + shift1[c]*ai);
  }
}

// =====================================================================
extern "C" void kernel_launch(void* const* d_in, const int* in_sizes, int n_in,
                              void* d_out, int out_size, void* d_ws, size_t ws_size,
                              hipStream_t stream)
{
  const float* x    = (const float*)d_in[0];
  const int*   ei   = (const int*)d_in[1];
  const float* g1w  = (const float*)d_in[2];
  const float* g1b  = (const float*)d_in[3];
  const float* m1w  = (const float*)d_in[4];
  const float* m1b  = (const float*)d_in[5];
  const float* bn1g = (const float*)d_in[6];
  const float* bn1b = (const float*)d_in[7];
  const float* g2w  = (const float*)d_in[8];
  const float* g2b  = (const float*)d_in[9];
  const float* m2w  = (const float*)d_in[10];
  const float* m2b  = (const float*)d_in[11];
  const float* bn2g = (const float*)d_in[12];
  const float* bn2b = (const float*)d_in[13];
  const float* fcw  = (const float*)d_in[14];
  const float* fcb  = (const float*)d_in[15];

  char* wsp = (char*)d_ws;
  size_t off = 0;
  auto alloc = [&](size_t bytes) -> char* {
    char* p = wsp + off;
    off = (off + bytes + 255) & ~(size_t)255;
    return p;
  };
  float* Adj    = (float*)alloc(J_*J_*4);
  float* aind   = (float*)alloc(J_*4);
  int*   csroff = (int*)alloc((J_+1)*4);
  int*   csredg = (int*)alloc(E_*4);
  float* scale1 = (float*)alloc(H_*4);
  float* shift1 = (float*)alloc(H_*4);
  float* scale2 = (float*)alloc(H_*4);
  float* shift2 = (float*)alloc(H_*4);
  float* crow1  = (float*)alloc(H_*4);
  float* cvec   = (float*)alloc(NOUT_*4);
  double* partial = (double*)alloc((size_t)NP_*H_*2*8);   // 2 MB, reused BN1/BN2
  u16* g1T  = (u16*)alloc((size_t)H_*NIN_*2);
  u16* g2T  = (u16*)alloc((size_t)H_*H_*2);
  u16* W1aT = (u16*)alloc((size_t)H_*H_*2);
  u16* W1bT = (u16*)alloc((size_t)H_*H_*2);
  u16* W2aT = (u16*)alloc((size_t)H_*H_*2);
  u16* W2bT = (u16*)alloc((size_t)H_*H_*2);
  u16* WcT  = (u16*)alloc((size_t)H_*H_*2);
  u16* fcT  = (u16*)alloc((size_t)NOUT_*H_*2);
  u16* Ax   = (u16*)alloc((size_t)M_NODE*NIN_*2);
  u16* h    = (u16*)alloc((size_t)M_NODE*H_*2);
  float* hs = (float*)alloc((size_t)M_NODE*H_*4);
  float* hd = (float*)alloc((size_t)M_NODE*H_*4);
  float* node_raw = (float*)alloc((size_t)M_NODE*H_*4);
  u16* An   = (u16*)alloc((size_t)M_NODE*H_*2);
  u16* h2   = (u16*)alloc((size_t)M_NODE*H_*2);
  float* h2s = (float*)alloc((size_t)M_NODE*H_*4);
  float* h2d = (float*)alloc((size_t)M_NODE*H_*4);
  u16* e_raw = (u16*)alloc((size_t)M_EDGE*H_*2);   // raw post-ReLU e (x_skip pre-BN)
  u16* e2    = (u16*)alloc((size_t)M_EDGE*H_*2);   // raw post-ReLU e2 (pre-BN2)
  if (off > ws_size) return;   // diagnostic: out stays 0

  const int* srcI = ei;
  const int* dstI = ei + E_;
  float* outF = (float*)d_out;   // output is float32

  build_graph<<<1, 256, 0, stream>>>(ei, Adj, aind, csroff, csredg);

  transpose_cv<<<(NIN_*H_+255)/256, 256, 0, stream>>>(g1w, g1T, NIN_, H_);
  transpose_cv<<<(H_*H_+255)/256, 256, 0, stream>>>(g2w, g2T, H_, H_);
  transpose_cv<<<(H_*H_+255)/256, 256, 0, stream>>>(m1w, W1aT, H_, H_);
  transpose_cv<<<(H_*H_+255)/256, 256, 0, stream>>>(m1w + (size_t)H_*H_, W1bT, H_, H_);
  transpose_cv<<<(H_*H_+255)/256, 256, 0, stream>>>(m2w, W2aT, H_, H_);
  transpose_cv<<<(H_*H_+255)/256, 256, 0, stream>>>(m2w + (size_t)H_*H_, W2bT, H_, H_);

  ax_kernel<<<M_NODE, 192, 0, stream>>>(Adj, x, Ax);

  // h = relu(Ax @ gcn1_w + b1)   [M=1856, K=192, N=512]
  gemm64<1><<<dim3(M_NODE/64, H_/64), 256, 0, stream>>>(Ax, g1T, M_NODE, H_, NIN_,
      g1b, nullptr, nullptr, nullptr, nullptr, nullptr, h, nullptr);
  // hs = h @ W1a, hd = h @ W1b (f32)
  gemm64<0><<<dim3(M_NODE/64, H_/64), 256, 0, stream>>>(h, W1aT, M_NODE, H_, H_,
      nullptr, nullptr, nullptr, nullptr, nullptr, nullptr, nullptr, hs);
  gemm64<0><<<dim3(M_NODE/64, H_/64), 256, 0, stream>>>(h, W1bT, M_NODE, H_, H_,
      nullptr, nullptr, nullptr, nullptr, nullptr, nullptr, nullptr, hd);
  // e_raw = relu(hs[src] + hd[dst] + b1)
  edge1_kernel<<<M_EDGE/16, 256, 0, stream>>>(hs, hd, m1b, srcI, dstI, e_raw);
  // BN1 stats (deterministic 2-pass, f64) -> scale1/shift1 (folded, never applied)
  stats_scan<<<NP_, 256, 0, stream>>>(e_raw, partial);
  bn_fin<<<1, 512, 0, stream>>>(partial, bn1g, bn1b, scale1, shift1);
  build_wc<<<H_, 256, 0, stream>>>(m2w, m2b, scale1, shift1, WcT, crow1);
  // edge2node on RAW e; BN1 fold applied inside an_kernel via scale1/shift1/aind
  scatter_kernel<<<M_NODE, 256, 0, stream>>>(e_raw, csroff, csredg, node_raw);
  an_kernel<<<M_NODE, 256, 0, stream>>>(Adj, node_raw, scale1, shift1, aind, An);
  // h2 = relu(An @ gcn2_w + b2)
  gemm64<1><<<dim3(M_NODE/64, H_/64), 256, 0, stream>>>(An, g2T, M_NODE, H_, H_,
      g2b, nullptr, nullptr, nullptr, nullptr, nullptr, h2, nullptr);
  gemm64<0><<<dim3(M_NODE/64, H_/64), 256, 0, stream>>>(h2, W2aT, M_NODE, H_, H_,
      nullptr, nullptr, nullptr, nullptr, nullptr, nullptr, nullptr, h2s);
  gemm64<0><<<dim3(M_NODE/64, H_/64), 256, 0, stream>>>(h2, W2bT, M_NODE, H_, H_,
      nullptr, nullptr, nullptr, nullptr, nullptr, nullptr, nullptr, h2d);
  // e2 = relu(e_raw @ WcT(scaled) + h2s[src] + h2d[dst] + crow1)   [the big GEMM]
  gemm64<2><<<dim3(M_EDGE/64, H_/64), 256, 0, stream>>>(e_raw, WcT, M_EDGE, H_, H_,
      nullptr, h2s, h2d, crow1, srcI, dstI, e2, nullptr);
  // BN2 stats -> scale2/shift2 (folded into fc)
  stats_scan<<<NP_, 256, 0, stream>>>(e2, partial);
  bn_fin<<<1, 512, 0, stream>>>(partial, bn2g, bn2b, scale2, shift2);
  build_fc<<<NOUT_, 256, 0, stream>>>(fcw, fcb, scale2, shift2, fcT, cvec);
  // out = e2 @ fcT(scaled) + cvec   (float32 output)
  gemm64<3><<<dim3(M_EDGE/64, NOUT_/64), 256, 0, stream>>>(e2, fcT, M_EDGE, NOUT_, H_,
      nullptr, nullptr, nullptr, cvec, nullptr, nullptr, nullptr, outF);
}

// Round 11
// 557.480 us; speedup vs baseline: 18.4249x; 1.3525x over previous
//
#include <hip/hip_runtime.h>
#include <stdint.h>

#define J_ 58
#define E_ 3306
#define B_ 32
#define NIN_ 192
#define H_ 512
#define NOUT_ 128
#define M_EDGE (B_*E_)   /* 105792 */
#define M_PAD  (M_EDGE + 64) /* 105856 = 827*128 */
#define M_NODE (B_*J_)   /* 1856  */
#define NSLOT 64

typedef unsigned short u16;
typedef __attribute__((ext_vector_type(8))) short short8v;
typedef __attribute__((ext_vector_type(4))) float f32x4;

__device__ __forceinline__ float b2f(u16 u){ return __uint_as_float(((uint32_t)u)<<16); }
__device__ __forceinline__ u16 f2b(float f){
  uint32_t u = __float_as_uint(f);
  u += 0x7FFFu + ((u>>16)&1u);
  return (u16)(u>>16);
}
__device__ __forceinline__ void async16(const void* g, void* l){
  __builtin_amdgcn_global_load_lds((const __attribute__((address_space(1))) uint32_t*)g,
                                   (__attribute__((address_space(3))) uint32_t*)l, 16, 0, 0);
}

// ---------------- graph preprocessing (1 block) ----------------
__global__ __launch_bounds__(256) void build_graph(const int* __restrict__ ei,
    float* __restrict__ Adj, float* __restrict__ aind,
    int* __restrict__ csroff, int* __restrict__ csredg)
{
  __shared__ float adj[J_][J_];
  __shared__ int   deg[J_];
  __shared__ float dinv[J_];
  __shared__ int   off[J_+1];
  __shared__ int   cur[J_];
  const int t = threadIdx.x;
  const int* srcI = ei;
  const int* dstI = ei + E_;
  for (int i = t; i < J_*J_; i += 256) adj[i/J_][i%J_] = 0.f;
  if (t < J_) { deg[t] = 0; cur[t] = 0; }
  __syncthreads();
  for (int e = t; e < E_; e += 256) {
    atomicAdd(&adj[dstI[e]][srcI[e]], 1.f);
    atomicAdd(&deg[dstI[e]], 1);
  }
  __syncthreads();
  if (t < J_) adj[t][t] += 1.f;
  __syncthreads();
  if (t < J_) {
    float s = 0.f;
    for (int j = 0; j < J_; ++j) s += adj[t][j];
    dinv[t] = rsqrtf(s);
  }
  __syncthreads();
  for (int i = t; i < J_*J_; i += 256) {
    int r = i / J_, c = i % J_;
    Adj[i] = dinv[r]*adj[r][c]*dinv[c];
  }
  if (t < J_) {
    float s = 0.f;
    for (int j = 0; j < J_; ++j) s += dinv[t]*adj[t][j]*dinv[j]*(float)deg[j];
    aind[t] = s;
  }
  if (t == 0) {
    off[0] = 0;
    for (int n = 0; n < J_; ++n) off[n+1] = off[n] + deg[n];
  }
  __syncthreads();
  if (t <= J_) csroff[t] = off[t];
  for (int e = t; e < E_; e += 256) {
    int d = dstI[e];
    int p = atomicAdd(&cur[d], 1);
    csredg[off[d] + p] = e;
  }
}

// -------- weight convert+transpose f32 [K,N] -> bf16 [N,K] --------
__global__ __launch_bounds__(256) void transpose_cv(const float* __restrict__ src,
    u16* __restrict__ dst, int K, int N)
{
  int idx = blockIdx.x*256 + threadIdx.x;
  if (idx >= K*N) return;
  int k = idx / N, n = idx - k*N;
  dst[(size_t)n*K + k] = f2b(src[idx]);
}

// ---------------- Ax = A @ x  (f32 x -> bf16 out) ----------------
__global__ __launch_bounds__(192) void ax_kernel(const float* __restrict__ Adj,
    const float* __restrict__ x, u16* __restrict__ Ax)
{
  int bi = blockIdx.x;            // b*J_ + i
  int b = bi / J_, i = bi - b*J_;
  __shared__ float Arow[J_];
  if (threadIdx.x < J_) Arow[threadIdx.x] = Adj[i*J_ + threadIdx.x];
  __syncthreads();
  int f = threadIdx.x;
  const float* xb = x + (size_t)b*J_*NIN_ + f;
  float acc = 0.f;
  for (int j = 0; j < J_; ++j) acc += Arow[j]*xb[(size_t)j*NIN_];
  Ax[(size_t)bi*NIN_ + f] = f2b(acc);
}

// ---------------- 64x64 MFMA GEMM (reg-staged), node-sized GEMMs ----------------
// MODE 0: outF = raw f32;  MODE 1: outB = bf16(relu(acc + bias[n]))
template<int MODE>
__global__ __launch_bounds__(256) void gemm64(
    const u16* __restrict__ Aop, const u16* __restrict__ Bt,
    const int M, const int N, const int K,
    const float* __restrict__ bias,
    u16* __restrict__ outB, float* __restrict__ outF)
{
  __shared__ __align__(16) u16 Al[64*32];
  __shared__ __align__(16) u16 Bl[64*32];
  const int tid = threadIdx.x;
  const int w = tid >> 6, l = tid & 63;
  const int row0 = blockIdx.x * 64, col0 = blockIdx.y * 64;
  f32x4 acc[4] = {};
  const u16* ag = Aop + (size_t)(row0 + (tid>>2))*K + (tid&3)*8;
  const u16* bg = Bt  + (size_t)(col0 + (tid>>2))*K + (tid&3)*8;
  const int fr = l & 15, fg = l >> 4;
  const int nk = K >> 5;
  for (int kt = 0; kt < nk; ++kt) {
    short8v av = *(const short8v*)ag;
    short8v bv = *(const short8v*)bg;
    ag += 32; bg += 32;
    __syncthreads();
    *(short8v*)(Al + tid*8) = av;
    *(short8v*)(Bl + tid*8) = bv;
    __syncthreads();
    short8v a = *(const short8v*)(Al + (w*16 + fr)*32 + fg*8);
#pragma unroll
    for (int nt = 0; nt < 4; ++nt) {
      short8v b = *(const short8v*)(Bl + (nt*16 + fr)*32 + fg*8);
      acc[nt] = __builtin_amdgcn_mfma_f32_16x16x32_bf16(a, b, acc[nt], 0, 0, 0);
    }
  }
#pragma unroll
  for (int nt = 0; nt < 4; ++nt) {
    int gc = col0 + nt*16 + fr;
    float bv = (MODE == 1) ? bias[gc] : 0.f;
#pragma unroll
    for (int r = 0; r < 4; ++r) {
      int gr = row0 + w*16 + fg*4 + r;
      if (MODE == 0) outF[(size_t)gr*N + gc] = acc[nt][r];
      else           outB[(size_t)gr*N + gc] = f2b(fmaxf(acc[nt][r] + bv, 0.f));
    }
  }
}

// ------ 128x128 MFMA GEMM, global_load_lds staging, 4 waves (2x2), BK=32 ------
// MODE 2: e2 = bf16(relu(acc + h2s[b,src,n] + h2d[b,dst,n] + crow[n])), BN2 stats
// MODE 3: outF = f32(acc + crow[n])   (final output, N=128)
// Rows padded to M_PAD; stores/stats guarded by m < M_EDGE.
template<int MODE>
__global__ __launch_bounds__(256) void gemm128(
    const u16* __restrict__ Aop, const u16* __restrict__ Bt,
    const int N, const int K,
    const float* __restrict__ g1, const float* __restrict__ g2,
    const float* __restrict__ crow,
    const int* __restrict__ srcI, const int* __restrict__ dstI,
    double* __restrict__ sumslot, double* __restrict__ sqslot,
    u16* __restrict__ outB, float* __restrict__ outF)
{
  __shared__ __align__(16) u16 Al[128*32];   // 8 KB
  __shared__ __align__(16) u16 Bl[128*32];   // 8 KB
  const int tid = threadIdx.x;
  const int w = tid >> 6, l = tid & 63;
  const int wm = w >> 1, wn = w & 1;         // 2x2 wave grid
  const int row0 = blockIdx.x * 128, col0 = blockIdx.y * 128;
  const int fr = l & 15, fg = l >> 4;
  f32x4 acc[4][4] = {};
  // staging: lane l covers LDS row (l>>2) within wave stripe, k (l&3)*8
  const int srow = l >> 2, skoff = (l & 3) * 8;
  const u16* agA = Aop + (size_t)(row0 + w*16 + srow)*K + skoff;
  const u16* agB = Bt  + (size_t)(col0 + w*16 + srow)*K + skoff;
  const size_t rstep = (size_t)64 * K;
  u16* ldsA0 = Al + w*512;          // wave-uniform bases (HW appends lane*16B)
  u16* ldsA1 = Al + 2048 + w*512;
  u16* ldsB0 = Bl + w*512;
  u16* ldsB1 = Bl + 2048 + w*512;
  const int nk = K >> 5;
  for (int kt = 0; kt < nk; ++kt) {
    __syncthreads();                 // previous consume done
    async16(agA,         ldsA0);     // A rows 0-63
    async16(agA + rstep, ldsA1);     // A rows 64-127
    async16(agB,         ldsB0);     // B rows 0-63
    async16(agB + rstep, ldsB1);     // B rows 64-127
    agA += 32; agB += 32;
    __syncthreads();                 // vmcnt drained -> tiles visible
    short8v a[4], b[4];
#pragma unroll
    for (int i = 0; i < 4; ++i)
      a[i] = *(const short8v*)(Al + (wm*64 + i*16 + fr)*32 + fg*8);
#pragma unroll
    for (int j = 0; j < 4; ++j)
      b[j] = *(const short8v*)(Bl + (wn*64 + j*16 + fr)*32 + fg*8);
#pragma unroll
    for (int i = 0; i < 4; ++i)
#pragma unroll
      for (int j = 0; j < 4; ++j)
        acc[i][j] = __builtin_amdgcn_mfma_f32_16x16x32_bf16(a[i], b[j], acc[i][j], 0, 0, 0);
  }

  if (MODE == 2) {
    int mr[4][4];
    uint32_t off1[4][4], off2[4][4];
#pragma unroll
    for (int i = 0; i < 4; ++i)
#pragma unroll
      for (int r = 0; r < 4; ++r) {
        int m = row0 + wm*64 + i*16 + fg*4 + r;
        mr[i][r] = m;
        int mm = (m < M_EDGE) ? m : 0;
        uint32_t bb = (uint32_t)mm / E_;
        uint32_t ke = (uint32_t)mm - bb*E_;
        off1[i][r] = (bb*J_ + (uint32_t)srcI[ke])*H_;
        off2[i][r] = (bb*J_ + (uint32_t)dstI[ke])*H_;
      }
    const int slot = blockIdx.x & (NSLOT-1);
#pragma unroll
    for (int j = 0; j < 4; ++j) {
      int gc = col0 + wn*64 + j*16 + fr;
      float cr = crow[gc];
      double s = 0.0, q = 0.0;
#pragma unroll
      for (int i = 0; i < 4; ++i)
#pragma unroll
        for (int r = 0; r < 4; ++r) {
          float v = acc[i][j][r] + g1[off1[i][r] + gc] + g2[off2[i][r] + gc] + cr;
          v = fmaxf(v, 0.f);
          if (mr[i][r] < M_EDGE) {
            outB[(size_t)mr[i][r]*N + gc] = f2b(v);
            double vd = (double)v;
            s += vd; q += vd*vd;
          }
        }
      s += __shfl_xor(s, 16); s += __shfl_xor(s, 32);
      q += __shfl_xor(q, 16); q += __shfl_xor(q, 32);
      if (fg == 0) {
        atomicAdd(&sumslot[(size_t)slot*H_ + gc], s);
        atomicAdd(&sqslot [(size_t)slot*H_ + gc], q);
      }
    }
  } else { // MODE 3
#pragma unroll
    for (int j = 0; j < 4; ++j) {
      int gc = col0 + wn*64 + j*16 + fr;
      float cr = crow[gc];
#pragma unroll
      for (int i = 0; i < 4; ++i)
#pragma unroll
        for (int r = 0; r < 4; ++r) {
          int m = row0 + wm*64 + i*16 + fg*4 + r;
          if (m < M_EDGE) outF[(size_t)m*N + gc] = acc[i][j][r] + cr;
        }
    }
  }
}

// ------- edge assembly 1: e = relu(hs[src]+hd[dst]+b1) + fused BN1 stats -------
__global__ __launch_bounds__(256) void edge1_kernel(const float* __restrict__ hs,
    const float* __restrict__ hd, const float* __restrict__ b1,
    const int* __restrict__ srcI, const int* __restrict__ dstI,
    u16* __restrict__ e_raw, double* __restrict__ sumslot, double* __restrict__ sqslot)
{
  const int t = threadIdx.x;
  const int row0 = blockIdx.x * 16;
  float bv0 = b1[t], bv1 = b1[t+256];
  double s0=0.0,q0=0.0,s1=0.0,q1=0.0;
  for (int r = 0; r < 16; ++r) {
    int m = row0 + r;
    uint32_t bb = (uint32_t)m / E_;
    uint32_t ke = (uint32_t)m - bb*E_;
    const float* ps = hs + ((size_t)bb*J_ + srcI[ke])*H_;
    const float* pd = hd + ((size_t)bb*J_ + dstI[ke])*H_;
    float v0 = fmaxf(ps[t]     + pd[t]     + bv0, 0.f);
    float v1 = fmaxf(ps[t+256] + pd[t+256] + bv1, 0.f);
    e_raw[(size_t)m*H_ + t]       = f2b(v0);
    e_raw[(size_t)m*H_ + t + 256] = f2b(v1);
    double d0 = (double)v0, d1 = (double)v1;
    s0 += d0; q0 += d0*d0; s1 += d1; q1 += d1*d1;
  }
  const int slot = blockIdx.x & (NSLOT-1);
  atomicAdd(&sumslot[(size_t)slot*H_ + t],     s0);
  atomicAdd(&sumslot[(size_t)slot*H_ + t+256], s1);
  atomicAdd(&sqslot [(size_t)slot*H_ + t],     q0);
  atomicAdd(&sqslot [(size_t)slot*H_ + t+256], q1);
}

// ---------------- BN finalize (f64 slots -> scale/shift) ----------------
__global__ __launch_bounds__(512) void bn_fin(const double* __restrict__ sumslot,
    const double* __restrict__ sqslot, const float* __restrict__ g, const float* __restrict__ b,
    float* __restrict__ scale, float* __restrict__ shift)
{
  int c = threadIdx.x;
  double s = 0.0, q = 0.0;
  for (int k = 0; k < NSLOT; ++k) { s += sumslot[(size_t)k*H_ + c]; q += sqslot[(size_t)k*H_ + c]; }
  const double invM = 1.0 / (double)M_EDGE;
  double mu = s * invM;
  double var = q * invM - mu*mu;
  if (var < 0.0) var = 0.0;
  float sc = g[c] * (float)(1.0 / sqrt(var + 1e-5));
  scale[c] = sc;
  shift[c] = b[c] - (float)mu*sc;
}

// ------- build scaled WcT bf16 [512,512] + crow1 (incl mlp2_b); m2w f32 -------
__global__ __launch_bounds__(256) void build_wc(const float* __restrict__ m2w,
    const float* __restrict__ m2b, const float* __restrict__ scale1, const float* __restrict__ shift1,
    u16* __restrict__ WcT, float* __restrict__ crow)
{
  int n = blockIdx.x;
  int t = threadIdx.x;
  __shared__ float red[256];
  float part = 0.f;
  for (int k = t; k < H_; k += 256) {
    float wv = m2w[(size_t)(2*H_ + k)*H_ + n];
    WcT[(size_t)n*H_ + k] = f2b(scale1[k]*wv);
    part += shift1[k]*wv;
  }
  red[t] = part; __syncthreads();
  for (int s = 128; s; s >>= 1) { if (t < s) red[t] += red[t+s]; __syncthreads(); }
  if (t == 0) crow[n] = red[0] + m2b[n];
}

// ------- build scaled fcT bf16 [128,512] + cvec (incl fc_b); fcw f32 -------
__global__ __launch_bounds__(256) void build_fc(const float* __restrict__ fcw,
    const float* __restrict__ fcb, const float* __restrict__ scale2, const float* __restrict__ shift2,
    u16* __restrict__ fcT, float* __restrict__ cvec)
{
  int n = blockIdx.x;
  int t = threadIdx.x;
  __shared__ float red[256];
  float part = 0.f;
  for (int k = t; k < H_; k += 256) {
    float wv = fcw[(size_t)k*NOUT_ + n];
    fcT[(size_t)n*H_ + k] = f2b(scale2[k]*wv);
    part += shift2[k]*wv;
  }
  red[t] = part; __syncthreads();
  for (int s = 128; s; s >>= 1) { if (t < s) red[t] += red[t+s]; __syncthreads(); }
  if (t == 0) cvec[n] = red[0] + fcb[n];
}

// ---------------- scatter: node_raw[b,n,:] = sum_{k: dst=n} e_raw[b,k,:] (PRE-BN) ----
__global__ __launch_bounds__(256) void scatter_kernel(const u16* __restrict__ e_raw,
    const int* __restrict__ csroff, const int* __restrict__ csredg, float* __restrict__ node_raw)
{
  int bi = blockIdx.x;
  int b = bi / J_, n = bi - b*J_;
  int beg = csroff[n], end = csroff[n+1];
  int c0 = threadIdx.x, c1 = threadIdx.x + 256;
  float a0 = 0.f, a1 = 0.f;
  for (int p = beg; p < end; ++p) {
    const u16* er = e_raw + ((size_t)b*E_ + csredg[p])*H_;
    a0 += b2f(er[c0]); a1 += b2f(er[c1]);
  }
  node_raw[(size_t)bi*H_ + c0] = a0;
  node_raw[(size_t)bi*H_ + c1] = a1;
}

// ------- An = bf16(scale1*(A @ node_raw) + shift1*aind[i])  (BN1 fold) -------
__global__ __launch_bounds__(256) void an_kernel(const float* __restrict__ Adj,
    const float* __restrict__ node_raw, const float* __restrict__ scale1,
    const float* __restrict__ shift1, const float* __restrict__ aind, u16* __restrict__ An)
{
  int bi = blockIdx.x;
  int b = bi / J_, i = bi - b*J_;
  __shared__ float Arow[J_];
  if (threadIdx.x < J_) Arow[threadIdx.x] = Adj[i*J_ + threadIdx.x];
  __syncthreads();
  float ai = aind[i];
#pragma unroll
  for (int h = 0; h < 2; ++h) {
    int c = threadIdx.x + h*256;
    const float* nb = node_raw + (size_t)b*J_*H_ + c;
    float acc = 0.f;
    for (int j = 0; j < J_; ++j) acc += Arow[j]*nb[(size_t)j*H_];
    An[(size_t)bi*H_ + c] = f2b(scale1[c]*acc + shift1[c]*ai);
  }
}

// =====================================================================
extern "C" void kernel_launch(void* const* d_in, const int* in_sizes, int n_in,
                              void* d_out, int out_size, void* d_ws, size_t ws_size,
                              hipStream_t stream)
{
  const float* x    = (const float*)d_in[0];
  const int*   ei   = (const int*)d_in[1];
  const float* g1w  = (const float*)d_in[2];
  const float* g1b  = (const float*)d_in[3];
  const float* m1w  = (const float*)d_in[4];
  const float* m1b  = (const float*)d_in[5];
  const float* bn1g = (const float*)d_in[6];
  const float* bn1b = (const float*)d_in[7];
  const float* g2w  = (const float*)d_in[8];
  const float* g2b  = (const float*)d_in[9];
  const float* m2w  = (const float*)d_in[10];
  const float* m2b  = (const float*)d_in[11];
  const float* bn2g = (const float*)d_in[12];
  const float* bn2b = (const float*)d_in[13];
  const float* fcw  = (const float*)d_in[14];
  const float* fcb  = (const float*)d_in[15];

  char* wsp = (char*)d_ws;
  size_t off = 0;
  auto alloc = [&](size_t bytes) -> char* {
    char* p = wsp + off;
    off = (off + bytes + 255) & ~(size_t)255;
    return p;
  };
  float* Adj    = (float*)alloc(J_*J_*4);
  float* aind   = (float*)alloc(J_*4);
  int*   csroff = (int*)alloc((J_+1)*4);
  int*   csredg = (int*)alloc(E_*4);
  float* scale1 = (float*)alloc(H_*4);
  float* shift1 = (float*)alloc(H_*4);
  float* scale2 = (float*)alloc(H_*4);
  float* shift2 = (float*)alloc(H_*4);
  float* crow1  = (float*)alloc(H_*4);
  float* cvec   = (float*)alloc(NOUT_*4);
  double* slots = (double*)alloc((size_t)4*NSLOT*H_*8);   // sum1,sq1,sum2,sq2
  double* sum1 = slots;
  double* sq1  = slots + (size_t)NSLOT*H_;
  double* sum2 = slots + (size_t)2*NSLOT*H_;
  double* sq2  = slots + (size_t)3*NSLOT*H_;
  u16* g1T  = (u16*)alloc((size_t)H_*NIN_*2);
  u16* g2T  = (u16*)alloc((size_t)H_*H_*2);
  u16* W1aT = (u16*)alloc((size_t)H_*H_*2);
  u16* W1bT = (u16*)alloc((size_t)H_*H_*2);
  u16* W2aT = (u16*)alloc((size_t)H_*H_*2);
  u16* W2bT = (u16*)alloc((size_t)H_*H_*2);
  u16* WcT  = (u16*)alloc((size_t)H_*H_*2);
  u16* fcT  = (u16*)alloc((size_t)NOUT_*H_*2);
  u16* Ax   = (u16*)alloc((size_t)M_NODE*NIN_*2);
  u16* h    = (u16*)alloc((size_t)M_NODE*H_*2);
  float* hs = (float*)alloc((size_t)M_NODE*H_*4);
  float* hd = (float*)alloc((size_t)M_NODE*H_*4);
  float* node_raw = (float*)alloc((size_t)M_NODE*H_*4);
  u16* An   = (u16*)alloc((size_t)M_NODE*H_*2);
  u16* h2   = (u16*)alloc((size_t)M_NODE*H_*2);
  float* h2s = (float*)alloc((size_t)M_NODE*H_*4);
  float* h2d = (float*)alloc((size_t)M_NODE*H_*4);
  u16* e_raw = (u16*)alloc((size_t)M_PAD*H_*2);   // raw post-ReLU e (padded rows)
  u16* e2    = (u16*)alloc((size_t)M_PAD*H_*2);   // raw post-ReLU e2 (padded rows)
  if (off > ws_size) return;   // diagnostic: out stays 0

  const int* srcI = ei;
  const int* dstI = ei + E_;
  float* outF = (float*)d_out;   // output is float32

  hipMemsetAsync(slots, 0, (size_t)4*NSLOT*H_*8, stream);
  build_graph<<<1, 256, 0, stream>>>(ei, Adj, aind, csroff, csredg);

  transpose_cv<<<(NIN_*H_+255)/256, 256, 0, stream>>>(g1w, g1T, NIN_, H_);
  transpose_cv<<<(H_*H_+255)/256, 256, 0, stream>>>(g2w, g2T, H_, H_);
  transpose_cv<<<(H_*H_+255)/256, 256, 0, stream>>>(m1w, W1aT, H_, H_);
  transpose_cv<<<(H_*H_+255)/256, 256, 0, stream>>>(m1w + (size_t)H_*H_, W1bT, H_, H_);
  transpose_cv<<<(H_*H_+255)/256, 256, 0, stream>>>(m2w, W2aT, H_, H_);
  transpose_cv<<<(H_*H_+255)/256, 256, 0, stream>>>(m2w + (size_t)H_*H_, W2bT, H_, H_);

  ax_kernel<<<M_NODE, 192, 0, stream>>>(Adj, x, Ax);

  // h = relu(Ax @ gcn1_w + b1)
  gemm64<1><<<dim3(M_NODE/64, H_/64), 256, 0, stream>>>(Ax, g1T, M_NODE, H_, NIN_,
      g1b, h, nullptr);
  // hs = h @ W1a, hd = h @ W1b (f32)
  gemm64<0><<<dim3(M_NODE/64, H_/64), 256, 0, stream>>>(h, W1aT, M_NODE, H_, H_,
      nullptr, nullptr, hs);
  gemm64<0><<<dim3(M_NODE/64, H_/64), 256, 0, stream>>>(h, W1bT, M_NODE, H_, H_,
      nullptr, nullptr, hd);
  // e_raw = relu(hs[src] + hd[dst] + b1)  + fused BN1 stats
  edge1_kernel<<<M_EDGE/16, 256, 0, stream>>>(hs, hd, m1b, srcI, dstI, e_raw, sum1, sq1);
  bn_fin<<<1, 512, 0, stream>>>(sum1, sq1, bn1g, bn1b, scale1, shift1);
  build_wc<<<H_, 256, 0, stream>>>(m2w, m2b, scale1, shift1, WcT, crow1);
  // edge2node on RAW e; BN1 fold applied in an_kernel
  scatter_kernel<<<M_NODE, 256, 0, stream>>>(e_raw, csroff, csredg, node_raw);
  an_kernel<<<M_NODE, 256, 0, stream>>>(Adj, node_raw, scale1, shift1, aind, An);
  // h2 = relu(An @ gcn2_w + b2)
  gemm64<1><<<dim3(M_NODE/64, H_/64), 256, 0, stream>>>(An, g2T, M_NODE, H_, H_,
      g2b, h2, nullptr);
  gemm64<0><<<dim3(M_NODE/64, H_/64), 256, 0, stream>>>(h2, W2aT, M_NODE, H_, H_,
      nullptr, nullptr, h2s);
  gemm64<0><<<dim3(M_NODE/64, H_/64), 256, 0, stream>>>(h2, W2bT, M_NODE, H_, H_,
      nullptr, nullptr, h2d);
  // e2 = relu(e_raw @ WcT(scaled) + h2s[src] + h2d[dst] + crow1) + fused BN2 stats
  gemm128<2><<<dim3(M_PAD/128, H_/128), 256, 0, stream>>>(e_raw, WcT, H_, H_,
      h2s, h2d, crow1, srcI, dstI, sum2, sq2, e2, nullptr);
  bn_fin<<<1, 512, 0, stream>>>(sum2, sq2, bn2g, bn2b, scale2, shift2);
  build_fc<<<NOUT_, 256, 0, stream>>>(fcw, fcb, scale2, shift2, fcT, cvec);
  // out = e2 @ fcT(scaled) + cvec   (float32 output)
  gemm128<3><<<dim3(M_PAD/128, NOUT_/128), 256, 0, stream>>>(e2, fcT, NOUT_, H_,
      nullptr, nullptr, cvec, nullptr, nullptr, nullptr, nullptr, nullptr, outF);
}

// Round 12
// 500.094 us; speedup vs baseline: 20.5392x; 1.1148x over previous
//
#include <hip/hip_runtime.h>
#include <stdint.h>

#define J_ 58
#define E_ 3306
#define B_ 32
#define NIN_ 192
#define H_ 512
#define NOUT_ 128
#define M_EDGE (B_*E_)   /* 105792 */
#define M_PAD  (M_EDGE + 64) /* 105856 = 827*128 */
#define M_NODE (B_*J_)   /* 1856  */
#define NSLOT 64

typedef unsigned short u16;
typedef __attribute__((ext_vector_type(8))) short short8v;
typedef __attribute__((ext_vector_type(4))) float f32x4;

__device__ __forceinline__ float b2f(u16 u){ return __uint_as_float(((uint32_t)u)<<16); }
__device__ __forceinline__ u16 f2b(float f){
  uint32_t u = __float_as_uint(f);
  u += 0x7FFFu + ((u>>16)&1u);
  return (u16)(u>>16);
}
__device__ __forceinline__ void async16(const void* g, void* l){
  __builtin_amdgcn_global_load_lds((const __attribute__((address_space(1))) uint32_t*)g,
                                   (__attribute__((address_space(3))) uint32_t*)l, 16, 0, 0);
}

// ---------------- graph preprocessing (1 block) ----------------
__global__ __launch_bounds__(256) void build_graph(const int* __restrict__ ei,
    float* __restrict__ Adj, float* __restrict__ aind,
    int* __restrict__ csroff, int* __restrict__ csredg)
{
  __shared__ float adj[J_][J_];
  __shared__ int   deg[J_];
  __shared__ float dinv[J_];
  __shared__ int   off[J_+1];
  __shared__ int   cur[J_];
  const int t = threadIdx.x;
  const int* srcI = ei;
  const int* dstI = ei + E_;
  for (int i = t; i < J_*J_; i += 256) adj[i/J_][i%J_] = 0.f;
  if (t < J_) { deg[t] = 0; cur[t] = 0; }
  __syncthreads();
  for (int e = t; e < E_; e += 256) {
    atomicAdd(&adj[dstI[e]][srcI[e]], 1.f);
    atomicAdd(&deg[dstI[e]], 1);
  }
  __syncthreads();
  if (t < J_) adj[t][t] += 1.f;
  __syncthreads();
  if (t < J_) {
    float s = 0.f;
    for (int j = 0; j < J_; ++j) s += adj[t][j];
    dinv[t] = rsqrtf(s);
  }
  __syncthreads();
  for (int i = t; i < J_*J_; i += 256) {
    int r = i / J_, c = i % J_;
    Adj[i] = dinv[r]*adj[r][c]*dinv[c];
  }
  if (t < J_) {
    float s = 0.f;
    for (int j = 0; j < J_; ++j) s += dinv[t]*adj[t][j]*dinv[j]*(float)deg[j];
    aind[t] = s;
  }
  if (t == 0) {
    off[0] = 0;
    for (int n = 0; n < J_; ++n) off[n+1] = off[n] + deg[n];
  }
  __syncthreads();
  if (t <= J_) csroff[t] = off[t];
  for (int e = t; e < E_; e += 256) {
    int d = dstI[e];
    int p = atomicAdd(&cur[d], 1);
    csredg[off[d] + p] = e;
  }
}

// -------- weight convert+transpose f32 [K,N] -> bf16 [N,K] --------
__global__ __launch_bounds__(256) void transpose_cv(const float* __restrict__ src,
    u16* __restrict__ dst, int K, int N)
{
  int idx = blockIdx.x*256 + threadIdx.x;
  if (idx >= K*N) return;
  int k = idx / N, n = idx - k*N;
  dst[(size_t)n*K + k] = f2b(src[idx]);
}

// ---------------- Ax = A @ x  (f32 x -> bf16 out) ----------------
__global__ __launch_bounds__(192) void ax_kernel(const float* __restrict__ Adj,
    const float* __restrict__ x, u16* __restrict__ Ax)
{
  int bi = blockIdx.x;            // b*J_ + i
  int b = bi / J_, i = bi - b*J_;
  __shared__ float Arow[J_];
  if (threadIdx.x < J_) Arow[threadIdx.x] = Adj[i*J_ + threadIdx.x];
  __syncthreads();
  int f = threadIdx.x;
  const float* xb = x + (size_t)b*J_*NIN_ + f;
  float acc = 0.f;
  for (int j = 0; j < J_; ++j) acc += Arow[j]*xb[(size_t)j*NIN_];
  Ax[(size_t)bi*NIN_ + f] = f2b(acc);
}

// ---------------- 64x64 MFMA GEMM (reg-staged), node-sized GEMMs ----------------
// MODE 0: outF = raw f32;  MODE 1: outB = bf16(relu(acc + bias[n]))
template<int MODE>
__global__ __launch_bounds__(256) void gemm64(
    const u16* __restrict__ Aop, const u16* __restrict__ Bt,
    const int M, const int N, const int K,
    const float* __restrict__ bias,
    u16* __restrict__ outB, float* __restrict__ outF)
{
  __shared__ __align__(16) u16 Al[64*32];
  __shared__ __align__(16) u16 Bl[64*32];
  const int tid = threadIdx.x;
  const int w = tid >> 6, l = tid & 63;
  const int row0 = blockIdx.x * 64, col0 = blockIdx.y * 64;
  f32x4 acc[4] = {};
  const u16* ag = Aop + (size_t)(row0 + (tid>>2))*K + (tid&3)*8;
  const u16* bg = Bt  + (size_t)(col0 + (tid>>2))*K + (tid&3)*8;
  const int fr = l & 15, fg = l >> 4;
  const int nk = K >> 5;
  for (int kt = 0; kt < nk; ++kt) {
    short8v av = *(const short8v*)ag;
    short8v bv = *(const short8v*)bg;
    ag += 32; bg += 32;
    __syncthreads();
    *(short8v*)(Al + tid*8) = av;
    *(short8v*)(Bl + tid*8) = bv;
    __syncthreads();
    short8v a = *(const short8v*)(Al + (w*16 + fr)*32 + fg*8);
#pragma unroll
    for (int nt = 0; nt < 4; ++nt) {
      short8v b = *(const short8v*)(Bl + (nt*16 + fr)*32 + fg*8);
      acc[nt] = __builtin_amdgcn_mfma_f32_16x16x32_bf16(a, b, acc[nt], 0, 0, 0);
    }
  }
#pragma unroll
  for (int nt = 0; nt < 4; ++nt) {
    int gc = col0 + nt*16 + fr;
    float bv = (MODE == 1) ? bias[gc] : 0.f;
#pragma unroll
    for (int r = 0; r < 4; ++r) {
      int gr = row0 + w*16 + fg*4 + r;
      if (MODE == 0) outF[(size_t)gr*N + gc] = acc[nt][r];
      else           outB[(size_t)gr*N + gc] = f2b(fmaxf(acc[nt][r] + bv, 0.f));
    }
  }
}

// ------ 128x128 MFMA GEMM, DOUBLE-BUFFERED global_load_lds, 4 waves (2x2) ------
// MODE 2: e2 = bf16(relu(acc + h2s[b,src,n] + h2d[b,dst,n] + crow[n])), BN2 stats
// MODE 3: outF = f32(acc + crow[n])   (final output, N=128)
template<int MODE>
__global__ __launch_bounds__(256, 3) void gemm128(
    const u16* __restrict__ Aop, const u16* __restrict__ Bt,
    const int N, const int K,
    const float* __restrict__ g1, const float* __restrict__ g2,
    const float* __restrict__ crow,
    const int* __restrict__ srcI, const int* __restrict__ dstI,
    double* __restrict__ sumslot, double* __restrict__ sqslot,
    u16* __restrict__ outB, float* __restrict__ outF)
{
  __shared__ __align__(16) u16 Al[2][128*32];   // 2 x 8 KB
  __shared__ __align__(16) u16 Bl[2][128*32];   // 2 x 8 KB
  const int tid = threadIdx.x;
  const int w = tid >> 6, l = tid & 63;
  const int wm = w >> 1, wn = w & 1;            // 2x2 wave grid
  const int row0 = blockIdx.x * 128, col0 = blockIdx.y * 128;
  const int fr = l & 15, fg = l >> 4;
  f32x4 acc[4][4] = {};
  const int srow = l >> 2, skoff = (l & 3) * 8;
  const u16* agA = Aop + (size_t)(row0 + w*16 + srow)*K + skoff;
  const u16* agB = Bt  + (size_t)(col0 + w*16 + srow)*K + skoff;
  const size_t rstep = (size_t)64 * K;
  const int nk = K >> 5;
  // prologue: stage K-tile 0 into buffer 0
  async16(agA,         &Al[0][w*512]);
  async16(agA + rstep, &Al[0][2048 + w*512]);
  async16(agB,         &Bl[0][w*512]);
  async16(agB + rstep, &Bl[0][2048 + w*512]);
  __syncthreads();                 // implicit vmcnt(0): tile 0 landed
  for (int kt = 0; kt < nk; ++kt) {
    const int cur = kt & 1, nxt = cur ^ 1;
    if (kt + 1 < nk) {             // prefetch tile kt+1 into the other buffer
      const u16* pa = agA + (kt+1)*32;
      const u16* pb = agB + (kt+1)*32;
      async16(pa,         &Al[nxt][w*512]);
      async16(pa + rstep, &Al[nxt][2048 + w*512]);
      async16(pb,         &Bl[nxt][w*512]);
      async16(pb + rstep, &Bl[nxt][2048 + w*512]);
    }
    short8v a[4], b[4];
#pragma unroll
    for (int i = 0; i < 4; ++i)
      a[i] = *(const short8v*)(&Al[cur][(wm*64 + i*16 + fr)*32 + fg*8]);
#pragma unroll
    for (int j = 0; j < 4; ++j)
      b[j] = *(const short8v*)(&Bl[cur][(wn*64 + j*16 + fr)*32 + fg*8]);
#pragma unroll
    for (int i = 0; i < 4; ++i)
#pragma unroll
      for (int j = 0; j < 4; ++j)
        acc[i][j] = __builtin_amdgcn_mfma_f32_16x16x32_bf16(a[i], b[j], acc[i][j], 0, 0, 0);
    __syncthreads();               // prefetch landed + all waves done with buf[cur]
  }

  if (MODE == 2) {
    int mr[4][4];
    uint32_t off1[4][4], off2[4][4];
#pragma unroll
    for (int i = 0; i < 4; ++i)
#pragma unroll
      for (int r = 0; r < 4; ++r) {
        int m = row0 + wm*64 + i*16 + fg*4 + r;
        mr[i][r] = m;
        int mm = (m < M_EDGE) ? m : 0;
        uint32_t bb = (uint32_t)mm / E_;
        uint32_t ke = (uint32_t)mm - bb*E_;
        off1[i][r] = (bb*J_ + (uint32_t)srcI[ke])*H_;
        off2[i][r] = (bb*J_ + (uint32_t)dstI[ke])*H_;
      }
    const int slot = blockIdx.x & (NSLOT-1);
#pragma unroll
    for (int j = 0; j < 4; ++j) {
      int gc = col0 + wn*64 + j*16 + fr;
      float cr = crow[gc];
      double s = 0.0, q = 0.0;
#pragma unroll
      for (int i = 0; i < 4; ++i)
#pragma unroll
        for (int r = 0; r < 4; ++r) {
          float v = acc[i][j][r] + g1[off1[i][r] + gc] + g2[off2[i][r] + gc] + cr;
          v = fmaxf(v, 0.f);
          if (mr[i][r] < M_EDGE) {
            outB[(size_t)mr[i][r]*N + gc] = f2b(v);
            double vd = (double)v;
            s += vd; q += vd*vd;
          }
        }
      s += __shfl_xor(s, 16); s += __shfl_xor(s, 32);
      q += __shfl_xor(q, 16); q += __shfl_xor(q, 32);
      if (fg == 0) {
        atomicAdd(&sumslot[(size_t)slot*H_ + gc], s);
        atomicAdd(&sqslot [(size_t)slot*H_ + gc], q);
      }
    }
  } else { // MODE 3
#pragma unroll
    for (int j = 0; j < 4; ++j) {
      int gc = col0 + wn*64 + j*16 + fr;
      float cr = crow[gc];
#pragma unroll
      for (int i = 0; i < 4; ++i)
#pragma unroll
        for (int r = 0; r < 4; ++r) {
          int m = row0 + wm*64 + i*16 + fg*4 + r;
          if (m < M_EDGE) outF[(size_t)m*N + gc] = acc[i][j][r] + cr;
        }
    }
  }
}

// ------- edge assembly 1: e = relu(hs[src]+hd[dst]+b1) + fused BN1 stats -------
__global__ __launch_bounds__(256) void edge1_kernel(const float* __restrict__ hs,
    const float* __restrict__ hd, const float* __restrict__ b1,
    const int* __restrict__ srcI, const int* __restrict__ dstI,
    u16* __restrict__ e_raw, double* __restrict__ sumslot, double* __restrict__ sqslot)
{
  const int t = threadIdx.x;
  const int row0 = blockIdx.x * 16;
  float bv0 = b1[t], bv1 = b1[t+256];
  double s0=0.0,q0=0.0,s1=0.0,q1=0.0;
  for (int r = 0; r < 16; ++r) {
    int m = row0 + r;
    uint32_t bb = (uint32_t)m / E_;
    uint32_t ke = (uint32_t)m - bb*E_;
    const float* ps = hs + ((size_t)bb*J_ + srcI[ke])*H_;
    const float* pd = hd + ((size_t)bb*J_ + dstI[ke])*H_;
    float v0 = fmaxf(ps[t]     + pd[t]     + bv0, 0.f);
    float v1 = fmaxf(ps[t+256] + pd[t+256] + bv1, 0.f);
    e_raw[(size_t)m*H_ + t]       = f2b(v0);
    e_raw[(size_t)m*H_ + t + 256] = f2b(v1);
    double d0 = (double)v0, d1 = (double)v1;
    s0 += d0; q0 += d0*d0; s1 += d1; q1 += d1*d1;
  }
  const int slot = blockIdx.x & (NSLOT-1);
  atomicAdd(&sumslot[(size_t)slot*H_ + t],     s0);
  atomicAdd(&sumslot[(size_t)slot*H_ + t+256], s1);
  atomicAdd(&sqslot [(size_t)slot*H_ + t],     q0);
  atomicAdd(&sqslot [(size_t)slot*H_ + t+256], q1);
}

// ---------------- BN finalize (f64 slots -> scale/shift) ----------------
__global__ __launch_bounds__(512) void bn_fin(const double* __restrict__ sumslot,
    const double* __restrict__ sqslot, const float* __restrict__ g, const float* __restrict__ b,
    float* __restrict__ scale, float* __restrict__ shift)
{
  int c = threadIdx.x;
  double s = 0.0, q = 0.0;
  for (int k = 0; k < NSLOT; ++k) { s += sumslot[(size_t)k*H_ + c]; q += sqslot[(size_t)k*H_ + c]; }
  const double invM = 1.0 / (double)M_EDGE;
  double mu = s * invM;
  double var = q * invM - mu*mu;
  if (var < 0.0) var = 0.0;
  float sc = g[c] * (float)(1.0 / sqrt(var + 1e-5));
  scale[c] = sc;
  shift[c] = b[c] - (float)mu*sc;
}

// ------- build scaled WcT bf16 [512,512] + crow1 (incl mlp2_b); m2w f32 -------
__global__ __launch_bounds__(256) void build_wc(const float* __restrict__ m2w,
    const float* __restrict__ m2b, const float* __restrict__ scale1, const float* __restrict__ shift1,
    u16* __restrict__ WcT, float* __restrict__ crow)
{
  int n = blockIdx.x;
  int t = threadIdx.x;
  __shared__ float red[256];
  float part = 0.f;
  for (int k = t; k < H_; k += 256) {
    float wv = m2w[(size_t)(2*H_ + k)*H_ + n];
    WcT[(size_t)n*H_ + k] = f2b(scale1[k]*wv);
    part += shift1[k]*wv;
  }
  red[t] = part; __syncthreads();
  for (int s = 128; s; s >>= 1) { if (t < s) red[t] += red[t+s]; __syncthreads(); }
  if (t == 0) crow[n] = red[0] + m2b[n];
}

// ------- build scaled fcT bf16 [128,512] + cvec (incl fc_b); fcw f32 -------
__global__ __launch_bounds__(256) void build_fc(const float* __restrict__ fcw,
    const float* __restrict__ fcb, const float* __restrict__ scale2, const float* __restrict__ shift2,
    u16* __restrict__ fcT, float* __restrict__ cvec)
{
  int n = blockIdx.x;
  int t = threadIdx.x;
  __shared__ float red[256];
  float part = 0.f;
  for (int k = t; k < H_; k += 256) {
    float wv = fcw[(size_t)k*NOUT_ + n];
    fcT[(size_t)n*H_ + k] = f2b(scale2[k]*wv);
    part += shift2[k]*wv;
  }
  red[t] = part; __syncthreads();
  for (int s = 128; s; s >>= 1) { if (t < s) red[t] += red[t+s]; __syncthreads(); }
  if (t == 0) cvec[n] = red[0] + fcb[n];
}

// ---------------- scatter: node_raw[b,n,:] = sum_{k: dst=n} e_raw[b,k,:] (PRE-BN) ----
__global__ __launch_bounds__(256) void scatter_kernel(const u16* __restrict__ e_raw,
    const int* __restrict__ csroff, const int* __restrict__ csredg, float* __restrict__ node_raw)
{
  int bi = blockIdx.x;
  int b = bi / J_, n = bi - b*J_;
  int beg = csroff[n], end = csroff[n+1];
  int c0 = threadIdx.x, c1 = threadIdx.x + 256;
  float a0 = 0.f, a1 = 0.f;
  for (int p = beg; p < end; ++p) {
    const u16* er = e_raw + ((size_t)b*E_ + csredg[p])*H_;
    a0 += b2f(er[c0]); a1 += b2f(er[c1]);
  }
  node_raw[(size_t)bi*H_ + c0] = a0;
  node_raw[(size_t)bi*H_ + c1] = a1;
}

// ------- An = bf16(scale1*(A @ node_raw) + shift1*aind[i])  (BN1 fold) -------
__global__ __launch_bounds__(256) void an_kernel(const float* __restrict__ Adj,
    const float* __restrict__ node_raw, const float* __restrict__ scale1,
    const float* __restrict__ shift1, const float* __restrict__ aind, u16* __restrict__ An)
{
  int bi = blockIdx.x;
  int b = bi / J_, i = bi - b*J_;
  __shared__ float Arow[J_];
  if (threadIdx.x < J_) Arow[threadIdx.x] = Adj[i*J_ + threadIdx.x];
  __syncthreads();
  float ai = aind[i];
#pragma unroll
  for (int h = 0; h < 2; ++h) {
    int c = threadIdx.x + h*256;
    const float* nb = node_raw + (size_t)b*J_*H_ + c;
    float acc = 0.f;
    for (int j = 0; j < J_; ++j) acc += Arow[j]*nb[(size_t)j*H_];
    An[(size_t)bi*H_ + c] = f2b(scale1[c]*acc + shift1[c]*ai);
  }
}

// =====================================================================
extern "C" void kernel_launch(void* const* d_in, const int* in_sizes, int n_in,
                              void* d_out, int out_size, void* d_ws, size_t ws_size,
                              hipStream_t stream)
{
  const float* x    = (const float*)d_in[0];
  const int*   ei   = (const int*)d_in[1];
  const float* g1w  = (const float*)d_in[2];
  const float* g1b  = (const float*)d_in[3];
  const float* m1w  = (const float*)d_in[4];
  const float* m1b  = (const float*)d_in[5];
  const float* bn1g = (const float*)d_in[6];
  const float* bn1b = (const float*)d_in[7];
  const float* g2w  = (const float*)d_in[8];
  const float* g2b  = (const float*)d_in[9];
  const float* m2w  = (const float*)d_in[10];
  const float* m2b  = (const float*)d_in[11];
  const float* bn2g = (const float*)d_in[12];
  const float* bn2b = (const float*)d_in[13];
  const float* fcw  = (const float*)d_in[14];
  const float* fcb  = (const float*)d_in[15];

  char* wsp = (char*)d_ws;
  size_t off = 0;
  auto alloc = [&](size_t bytes) -> char* {
    char* p = wsp + off;
    off = (off + bytes + 255) & ~(size_t)255;
    return p;
  };
  float* Adj    = (float*)alloc(J_*J_*4);
  float* aind   = (float*)alloc(J_*4);
  int*   csroff = (int*)alloc((J_+1)*4);
  int*   csredg = (int*)alloc(E_*4);
  float* scale1 = (float*)alloc(H_*4);
  float* shift1 = (float*)alloc(H_*4);
  float* scale2 = (float*)alloc(H_*4);
  float* shift2 = (float*)alloc(H_*4);
  float* crow1  = (float*)alloc(H_*4);
  float* cvec   = (float*)alloc(NOUT_*4);
  double* slots = (double*)alloc((size_t)4*NSLOT*H_*8);   // sum1,sq1,sum2,sq2
  double* sum1 = slots;
  double* sq1  = slots + (size_t)NSLOT*H_;
  double* sum2 = slots + (size_t)2*NSLOT*H_;
  double* sq2  = slots + (size_t)3*NSLOT*H_;
  u16* g1T  = (u16*)alloc((size_t)H_*NIN_*2);
  u16* g2T  = (u16*)alloc((size_t)H_*H_*2);
  u16* W1aT = (u16*)alloc((size_t)H_*H_*2);
  u16* W1bT = (u16*)alloc((size_t)H_*H_*2);
  u16* W2aT = (u16*)alloc((size_t)H_*H_*2);
  u16* W2bT = (u16*)alloc((size_t)H_*H_*2);
  u16* WcT  = (u16*)alloc((size_t)H_*H_*2);
  u16* fcT  = (u16*)alloc((size_t)NOUT_*H_*2);
  u16* Ax   = (u16*)alloc((size_t)M_NODE*NIN_*2);
  u16* h    = (u16*)alloc((size_t)M_NODE*H_*2);
  float* hs = (float*)alloc((size_t)M_NODE*H_*4);
  float* hd = (float*)alloc((size_t)M_NODE*H_*4);
  float* node_raw = (float*)alloc((size_t)M_NODE*H_*4);
  u16* An   = (u16*)alloc((size_t)M_NODE*H_*2);
  u16* h2   = (u16*)alloc((size_t)M_NODE*H_*2);
  float* h2s = (float*)alloc((size_t)M_NODE*H_*4);
  float* h2d = (float*)alloc((size_t)M_NODE*H_*4);
  u16* e_raw = (u16*)alloc((size_t)M_PAD*H_*2);   // raw post-ReLU e (padded rows)
  u16* e2    = (u16*)alloc((size_t)M_PAD*H_*2);   // raw post-ReLU e2 (padded rows)
  if (off > ws_size) return;   // diagnostic: out stays 0

  const int* srcI = ei;
  const int* dstI = ei + E_;
  float* outF = (float*)d_out;   // output is float32

  hipMemsetAsync(slots, 0, (size_t)4*NSLOT*H_*8, stream);
  build_graph<<<1, 256, 0, stream>>>(ei, Adj, aind, csroff, csredg);

  transpose_cv<<<(NIN_*H_+255)/256, 256, 0, stream>>>(g1w, g1T, NIN_, H_);
  transpose_cv<<<(H_*H_+255)/256, 256, 0, stream>>>(g2w, g2T, H_, H_);
  transpose_cv<<<(H_*H_+255)/256, 256, 0, stream>>>(m1w, W1aT, H_, H_);
  transpose_cv<<<(H_*H_+255)/256, 256, 0, stream>>>(m1w + (size_t)H_*H_, W1bT, H_, H_);
  transpose_cv<<<(H_*H_+255)/256, 256, 0, stream>>>(m2w, W2aT, H_, H_);
  transpose_cv<<<(H_*H_+255)/256, 256, 0, stream>>>(m2w + (size_t)H_*H_, W2bT, H_, H_);

  ax_kernel<<<M_NODE, 192, 0, stream>>>(Adj, x, Ax);

  // h = relu(Ax @ gcn1_w + b1)
  gemm64<1><<<dim3(M_NODE/64, H_/64), 256, 0, stream>>>(Ax, g1T, M_NODE, H_, NIN_,
      g1b, h, nullptr);
  // hs = h @ W1a, hd = h @ W1b (f32)
  gemm64<0><<<dim3(M_NODE/64, H_/64), 256, 0, stream>>>(h, W1aT, M_NODE, H_, H_,
      nullptr, nullptr, hs);
  gemm64<0><<<dim3(M_NODE/64, H_/64), 256, 0, stream>>>(h, W1bT, M_NODE, H_, H_,
      nullptr, nullptr, hd);
  // e_raw = relu(hs[src] + hd[dst] + b1)  + fused BN1 stats
  edge1_kernel<<<M_EDGE/16, 256, 0, stream>>>(hs, hd, m1b, srcI, dstI, e_raw, sum1, sq1);
  bn_fin<<<1, 512, 0, stream>>>(sum1, sq1, bn1g, bn1b, scale1, shift1);
  build_wc<<<H_, 256, 0, stream>>>(m2w, m2b, scale1, shift1, WcT, crow1);
  // edge2node on RAW e; BN1 fold applied in an_kernel
  scatter_kernel<<<M_NODE, 256, 0, stream>>>(e_raw, csroff, csredg, node_raw);
  an_kernel<<<M_NODE, 256, 0, stream>>>(Adj, node_raw, scale1, shift1, aind, An);
  // h2 = relu(An @ gcn2_w + b2)
  gemm64<1><<<dim3(M_NODE/64, H_/64), 256, 0, stream>>>(An, g2T, M_NODE, H_, H_,
      g2b, h2, nullptr);
  gemm64<0><<<dim3(M_NODE/64, H_/64), 256, 0, stream>>>(h2, W2aT, M_NODE, H_, H_,
      nullptr, nullptr, h2s);
  gemm64<0><<<dim3(M_NODE/64, H_/64), 256, 0, stream>>>(h2, W2bT, M_NODE, H_, H_,
      nullptr, nullptr, h2d);
  // e2 = relu(e_raw @ WcT(scaled) + h2s[src] + h2d[dst] + crow1) + fused BN2 stats
  gemm128<2><<<dim3(M_PAD/128, H_/128), 256, 0, stream>>>(e_raw, WcT, H_, H_,
      h2s, h2d, crow1, srcI, dstI, sum2, sq2, e2, nullptr);
  bn_fin<<<1, 512, 0, stream>>>(sum2, sq2, bn2g, bn2b, scale2, shift2);
  build_fc<<<NOUT_, 256, 0, stream>>>(fcw, fcb, scale2, shift2, fcT, cvec);
  // out = e2 @ fcT(scaled) + cvec   (float32 output)
  gemm128<3><<<dim3(M_PAD/128, NOUT_/128), 256, 0, stream>>>(e2, fcT, NOUT_, H_,
      nullptr, nullptr, cvec, nullptr, nullptr, nullptr, nullptr, nullptr, outF);
}

// Round 13
// 491.003 us; speedup vs baseline: 20.9195x; 1.0185x over previous
//
#include <hip/hip_runtime.h>
#include <stdint.h>

#define J_ 58
#define E_ 3306
#define B_ 32
#define NIN_ 192
#define H_ 512
#define NOUT_ 128
#define M_EDGE (B_*E_)   /* 105792 */
#define M_PAD  (M_EDGE + 64) /* 105856 = 827*128 */
#define M_NODE (B_*J_)   /* 1856  */
#define NSLOT 64

typedef unsigned short u16;
typedef __attribute__((ext_vector_type(8))) short short8v;
typedef __attribute__((ext_vector_type(4))) float f32x4;

__device__ __forceinline__ float b2f(u16 u){ return __uint_as_float(((uint32_t)u)<<16); }
__device__ __forceinline__ u16 f2b(float f){
  uint32_t u = __float_as_uint(f);
  u += 0x7FFFu + ((u>>16)&1u);
  return (u16)(u>>16);
}
__device__ __forceinline__ void async16(const void* g, void* l){
  __builtin_amdgcn_global_load_lds((const __attribute__((address_space(1))) uint32_t*)g,
                                   (__attribute__((address_space(3))) uint32_t*)l, 16, 0, 0);
}

// ---------------- graph preprocessing (1 block) ----------------
__global__ __launch_bounds__(256) void build_graph(const int* __restrict__ ei,
    float* __restrict__ Adj, float* __restrict__ aind,
    int* __restrict__ csroff, int* __restrict__ csredg)
{
  __shared__ float adj[J_][J_];
  __shared__ int   deg[J_];
  __shared__ float dinv[J_];
  __shared__ int   off[J_+1];
  __shared__ int   cur[J_];
  const int t = threadIdx.x;
  const int* srcI = ei;
  const int* dstI = ei + E_;
  for (int i = t; i < J_*J_; i += 256) adj[i/J_][i%J_] = 0.f;
  if (t < J_) { deg[t] = 0; cur[t] = 0; }
  __syncthreads();
  for (int e = t; e < E_; e += 256) {
    atomicAdd(&adj[dstI[e]][srcI[e]], 1.f);
    atomicAdd(&deg[dstI[e]], 1);
  }
  __syncthreads();
  if (t < J_) adj[t][t] += 1.f;
  __syncthreads();
  if (t < J_) {
    float s = 0.f;
    for (int j = 0; j < J_; ++j) s += adj[t][j];
    dinv[t] = rsqrtf(s);
  }
  __syncthreads();
  for (int i = t; i < J_*J_; i += 256) {
    int r = i / J_, c = i % J_;
    Adj[i] = dinv[r]*adj[r][c]*dinv[c];
  }
  if (t < J_) {
    float s = 0.f;
    for (int j = 0; j < J_; ++j) s += dinv[t]*adj[t][j]*dinv[j]*(float)deg[j];
    aind[t] = s;
  }
  if (t == 0) {
    off[0] = 0;
    for (int n = 0; n < J_; ++n) off[n+1] = off[n] + deg[n];
  }
  __syncthreads();
  if (t <= J_) csroff[t] = off[t];
  for (int e = t; e < E_; e += 256) {
    int d = dstI[e];
    int p = atomicAdd(&cur[d], 1);
    csredg[off[d] + p] = e;
  }
}

// -------- weight convert+transpose f32 [K,N] -> bf16 [N,K] --------
__global__ __launch_bounds__(256) void transpose_cv(const float* __restrict__ src,
    u16* __restrict__ dst, int K, int N)
{
  int idx = blockIdx.x*256 + threadIdx.x;
  if (idx >= K*N) return;
  int k = idx / N, n = idx - k*N;
  dst[(size_t)n*K + k] = f2b(src[idx]);
}

// -------- pair transpose: src [2H,H] f32 -> dst [2H][H] bf16 where
// dst[n'][k] = n'<H ? src[k][n'] : src[H+k][n'-H]   (stacked W_a^T ; W_b^T) --------
__global__ __launch_bounds__(256) void transpose_pair(const float* __restrict__ src,
    u16* __restrict__ dst)
{
  int idx = blockIdx.x*256 + threadIdx.x;
  if (idx >= 2*H_*H_) return;
  int np = idx / H_, k = idx - np*H_;
  float v = (np < H_) ? src[(size_t)k*H_ + np] : src[(size_t)(H_+k)*H_ + (np-H_)];
  dst[idx] = f2b(v);
}

// ---------------- Ax = A @ x  (f32 x -> bf16 out) ----------------
__global__ __launch_bounds__(192) void ax_kernel(const float* __restrict__ Adj,
    const float* __restrict__ x, u16* __restrict__ Ax)
{
  int bi = blockIdx.x;            // b*J_ + i
  int b = bi / J_, i = bi - b*J_;
  __shared__ float Arow[J_];
  if (threadIdx.x < J_) Arow[threadIdx.x] = Adj[i*J_ + threadIdx.x];
  __syncthreads();
  int f = threadIdx.x;
  const float* xb = x + (size_t)b*J_*NIN_ + f;
  float acc = 0.f;
  for (int j = 0; j < J_; ++j) acc += Arow[j]*xb[(size_t)j*NIN_];
  Ax[(size_t)bi*NIN_ + f] = f2b(acc);
}

// ---------------- 64x64 MFMA GEMM (reg-staged), node-sized GEMMs ----------------
// MODE 0: outF = raw f32;  MODE 1: outB = bf16(relu(acc + bias[n]))
template<int MODE>
__global__ __launch_bounds__(256) void gemm64(
    const u16* __restrict__ Aop, const u16* __restrict__ Bt,
    const int M, const int N, const int K,
    const float* __restrict__ bias,
    u16* __restrict__ outB, float* __restrict__ outF)
{
  __shared__ __align__(16) u16 Al[64*32];
  __shared__ __align__(16) u16 Bl[64*32];
  const int tid = threadIdx.x;
  const int w = tid >> 6, l = tid & 63;
  const int row0 = blockIdx.x * 64, col0 = blockIdx.y * 64;
  f32x4 acc[4] = {};
  const u16* ag = Aop + (size_t)(row0 + (tid>>2))*K + (tid&3)*8;
  const u16* bg = Bt  + (size_t)(col0 + (tid>>2))*K + (tid&3)*8;
  const int fr = l & 15, fg = l >> 4;
  const int nk = K >> 5;
  for (int kt = 0; kt < nk; ++kt) {
    short8v av = *(const short8v*)ag;
    short8v bv = *(const short8v*)bg;
    ag += 32; bg += 32;
    __syncthreads();
    *(short8v*)(Al + tid*8) = av;
    *(short8v*)(Bl + tid*8) = bv;
    __syncthreads();
    short8v a = *(const short8v*)(Al + (w*16 + fr)*32 + fg*8);
#pragma unroll
    for (int nt = 0; nt < 4; ++nt) {
      short8v b = *(const short8v*)(Bl + (nt*16 + fr)*32 + fg*8);
      acc[nt] = __builtin_amdgcn_mfma_f32_16x16x32_bf16(a, b, acc[nt], 0, 0, 0);
    }
  }
#pragma unroll
  for (int nt = 0; nt < 4; ++nt) {
    int gc = col0 + nt*16 + fr;
    float bv = (MODE == 1) ? bias[gc] : 0.f;
#pragma unroll
    for (int r = 0; r < 4; ++r) {
      int gr = row0 + w*16 + fg*4 + r;
      if (MODE == 0) outF[(size_t)gr*N + gc] = acc[nt][r];
      else           outB[(size_t)gr*N + gc] = f2b(fmaxf(acc[nt][r] + bv, 0.f));
    }
  }
}

// ------ 128x128 MFMA GEMM, 3-buffer pipelined global_load_lds, counted vmcnt ------
// MODE 2: e2 = bf16(relu(acc + gsd[.,src] + gsd[.,dst]+512 + crow[n])), BN2 stats
// MODE 3: outF = f32(acc + crow[n])   (final output, N=128)
// gsd has row stride 1024 (hsd layout: [:,0:512]=src-half, [:,512:1024]=dst-half).
template<int MODE>
__global__ __launch_bounds__(256, 3) void gemm128(
    const u16* __restrict__ Aop, const u16* __restrict__ Bt,
    const int N, const int K,
    const float* __restrict__ gsd,
    const float* __restrict__ crow,
    const int* __restrict__ srcI, const int* __restrict__ dstI,
    double* __restrict__ sumslot, double* __restrict__ sqslot,
    u16* __restrict__ outB, float* __restrict__ outF)
{
  __shared__ __align__(16) u16 Al[3*128*32];   // 3 x 8 KB
  __shared__ __align__(16) u16 Bl[3*128*32];   // 3 x 8 KB
  const int tid = threadIdx.x;
  const int w = tid >> 6, l = tid & 63;
  const int wm = w >> 1, wn = w & 1;            // 2x2 wave grid
  const int row0 = blockIdx.x * 128, col0 = blockIdx.y * 128;
  const int fr = l & 15, fg = l >> 4;
  f32x4 acc[4][4] = {};
  const int srow = l >> 2, skoff = (l & 3) * 8;
  const u16* agA = Aop + (size_t)(row0 + w*16 + srow)*K + skoff;
  const u16* agB = Bt  + (size_t)(col0 + w*16 + srow)*K + skoff;
  const size_t rstep = (size_t)64 * K;
  const int nk = K >> 5;   // 16
  // prologue: stage tiles 0,1 into buffers 0,1 (8 loads outstanding)
  async16(agA,          Al + w*512);
  async16(agA + rstep,  Al + 2048 + w*512);
  async16(agB,          Bl + w*512);
  async16(agB + rstep,  Bl + 2048 + w*512);
  async16(agA + 32,         Al + 4096 + w*512);
  async16(agA + 32 + rstep, Al + 4096 + 2048 + w*512);
  async16(agB + 32,         Bl + 4096 + w*512);
  async16(agB + 32 + rstep, Bl + 4096 + 2048 + w*512);
  int cur = 0;   // buffer consumed this iteration
  int pfb = 2;   // buffer receiving tile kt+2
  for (int kt = 0; kt < nk; ++kt) {
    if (kt + 1 < nk) asm volatile("s_waitcnt vmcnt(4)" ::: "memory");
    else             asm volatile("s_waitcnt vmcnt(0)" ::: "memory");
    asm volatile("s_barrier" ::: "memory");     // all waves: tile kt landed; prev reads done
    if (kt + 2 < nk) {
      const u16* pa = agA + (size_t)(kt+2)*32;
      const u16* pb = agB + (size_t)(kt+2)*32;
      u16* A0 = Al + pfb*4096;
      u16* B0 = Bl + pfb*4096;
      async16(pa,         A0 + w*512);
      async16(pa + rstep, A0 + 2048 + w*512);
      async16(pb,         B0 + w*512);
      async16(pb + rstep, B0 + 2048 + w*512);
    }
    const u16* Ac = Al + cur*4096;
    const u16* Bc = Bl + cur*4096;
    short8v a[4], b[4];
#pragma unroll
    for (int i = 0; i < 4; ++i)
      a[i] = *(const short8v*)(Ac + (wm*64 + i*16 + fr)*32 + fg*8);
#pragma unroll
    for (int j = 0; j < 4; ++j)
      b[j] = *(const short8v*)(Bc + (wn*64 + j*16 + fr)*32 + fg*8);
#pragma unroll
    for (int i = 0; i < 4; ++i)
#pragma unroll
      for (int j = 0; j < 4; ++j)
        acc[i][j] = __builtin_amdgcn_mfma_f32_16x16x32_bf16(a[i], b[j], acc[i][j], 0, 0, 0);
    cur = (cur == 2) ? 0 : cur + 1;
    pfb = (pfb == 2) ? 0 : pfb + 1;
  }

  if (MODE == 2) {
    int mr[4][4];
    uint32_t off1[4][4], off2[4][4];
#pragma unroll
    for (int i = 0; i < 4; ++i)
#pragma unroll
      for (int r = 0; r < 4; ++r) {
        int m = row0 + wm*64 + i*16 + fg*4 + r;
        mr[i][r] = m;
        int mm = (m < M_EDGE) ? m : 0;
        uint32_t bb = (uint32_t)mm / E_;
        uint32_t ke = (uint32_t)mm - bb*E_;
        off1[i][r] = (bb*J_ + (uint32_t)srcI[ke])*1024u;
        off2[i][r] = (bb*J_ + (uint32_t)dstI[ke])*1024u + 512u;
      }
    const int slot = blockIdx.x & (NSLOT-1);
#pragma unroll
    for (int j = 0; j < 4; ++j) {
      int gc = col0 + wn*64 + j*16 + fr;
      float cr = crow[gc];
      double s = 0.0, q = 0.0;
#pragma unroll
      for (int i = 0; i < 4; ++i)
#pragma unroll
        for (int r = 0; r < 4; ++r) {
          float v = acc[i][j][r] + gsd[off1[i][r] + gc] + gsd[off2[i][r] + gc] + cr;
          v = fmaxf(v, 0.f);
          if (mr[i][r] < M_EDGE) {
            outB[(size_t)mr[i][r]*N + gc] = f2b(v);
            double vd = (double)v;
            s += vd; q += vd*vd;
          }
        }
      s += __shfl_xor(s, 16); s += __shfl_xor(s, 32);
      q += __shfl_xor(q, 16); q += __shfl_xor(q, 32);
      if (fg == 0) {
        atomicAdd(&sumslot[(size_t)slot*H_ + gc], s);
        atomicAdd(&sqslot [(size_t)slot*H_ + gc], q);
      }
    }
  } else { // MODE 3
#pragma unroll
    for (int j = 0; j < 4; ++j) {
      int gc = col0 + wn*64 + j*16 + fr;
      float cr = crow[gc];
#pragma unroll
      for (int i = 0; i < 4; ++i)
#pragma unroll
        for (int r = 0; r < 4; ++r) {
          int m = row0 + wm*64 + i*16 + fg*4 + r;
          if (m < M_EDGE) outF[(size_t)m*N + gc] = acc[i][j][r] + cr;
        }
    }
  }
}

// ------- edge assembly 1: e = relu(hsd[src,c]+hsd[dst,512+c]+b1) + BN1 stats -------
__global__ __launch_bounds__(256) void edge1_kernel(const float* __restrict__ hsd,
    const float* __restrict__ b1,
    const int* __restrict__ srcI, const int* __restrict__ dstI,
    u16* __restrict__ e_raw, double* __restrict__ sumslot, double* __restrict__ sqslot)
{
  const int t = threadIdx.x;
  const int row0 = blockIdx.x * 16;
  float bv0 = b1[t], bv1 = b1[t+256];
  double s0=0.0,q0=0.0,s1=0.0,q1=0.0;
  for (int r = 0; r < 16; ++r) {
    int m = row0 + r;
    uint32_t bb = (uint32_t)m / E_;
    uint32_t ke = (uint32_t)m - bb*E_;
    const float* ps = hsd + ((size_t)bb*J_ + srcI[ke])*1024;
    const float* pd = hsd + ((size_t)bb*J_ + dstI[ke])*1024 + 512;
    float v0 = fmaxf(ps[t]     + pd[t]     + bv0, 0.f);
    float v1 = fmaxf(ps[t+256] + pd[t+256] + bv1, 0.f);
    e_raw[(size_t)m*H_ + t]       = f2b(v0);
    e_raw[(size_t)m*H_ + t + 256] = f2b(v1);
    double d0 = (double)v0, d1 = (double)v1;
    s0 += d0; q0 += d0*d0; s1 += d1; q1 += d1*d1;
  }
  const int slot = blockIdx.x & (NSLOT-1);
  atomicAdd(&sumslot[(size_t)slot*H_ + t],     s0);
  atomicAdd(&sumslot[(size_t)slot*H_ + t+256], s1);
  atomicAdd(&sqslot [(size_t)slot*H_ + t],     q0);
  atomicAdd(&sqslot [(size_t)slot*H_ + t+256], q1);
}

// ---------------- BN finalize (f64 slots -> scale/shift) ----------------
__global__ __launch_bounds__(512) void bn_fin(const double* __restrict__ sumslot,
    const double* __restrict__ sqslot, const float* __restrict__ g, const float* __restrict__ b,
    float* __restrict__ scale, float* __restrict__ shift)
{
  int c = threadIdx.x;
  double s = 0.0, q = 0.0;
  for (int k = 0; k < NSLOT; ++k) { s += sumslot[(size_t)k*H_ + c]; q += sqslot[(size_t)k*H_ + c]; }
  const double invM = 1.0 / (double)M_EDGE;
  double mu = s * invM;
  double var = q * invM - mu*mu;
  if (var < 0.0) var = 0.0;
  float sc = g[c] * (float)(1.0 / sqrt(var + 1e-5));
  scale[c] = sc;
  shift[c] = b[c] - (float)mu*sc;
}

// ------- build scaled WcT bf16 [512,512] + crow1 (incl mlp2_b); m2w f32 -------
__global__ __launch_bounds__(256) void build_wc(const float* __restrict__ m2w,
    const float* __restrict__ m2b, const float* __restrict__ scale1, const float* __restrict__ shift1,
    u16* __restrict__ WcT, float* __restrict__ crow)
{
  int n = blockIdx.x;
  int t = threadIdx.x;
  __shared__ float red[256];
  float part = 0.f;
  for (int k = t; k < H_; k += 256) {
    float wv = m2w[(size_t)(2*H_ + k)*H_ + n];
    WcT[(size_t)n*H_ + k] = f2b(scale1[k]*wv);
    part += shift1[k]*wv;
  }
  red[t] = part; __syncthreads();
  for (int s = 128; s; s >>= 1) { if (t < s) red[t] += red[t+s]; __syncthreads(); }
  if (t == 0) crow[n] = red[0] + m2b[n];
}

// ------- build scaled fcT bf16 [128,512] + cvec (incl fc_b); fcw f32 -------
__global__ __launch_bounds__(256) void build_fc(const float* __restrict__ fcw,
    const float* __restrict__ fcb, const float* __restrict__ scale2, const float* __restrict__ shift2,
    u16* __restrict__ fcT, float* __restrict__ cvec)
{
  int n = blockIdx.x;
  int t = threadIdx.x;
  __shared__ float red[256];
  float part = 0.f;
  for (int k = t; k < H_; k += 256) {
    float wv = fcw[(size_t)k*NOUT_ + n];
    fcT[(size_t)n*H_ + k] = f2b(scale2[k]*wv);
    part += shift2[k]*wv;
  }
  red[t] = part; __syncthreads();
  for (int s = 128; s; s >>= 1) { if (t < s) red[t] += red[t+s]; __syncthreads(); }
  if (t == 0) cvec[n] = red[0] + fcb[n];
}

// ---------------- scatter: node_raw[b,n,:] = sum_{k: dst=n} e_raw[b,k,:] (PRE-BN) ----
__global__ __launch_bounds__(256) void scatter_kernel(const u16* __restrict__ e_raw,
    const int* __restrict__ csroff, const int* __restrict__ csredg, float* __restrict__ node_raw)
{
  int bi = blockIdx.x;
  int b = bi / J_, n = bi - b*J_;
  int beg = csroff[n], end = csroff[n+1];
  int c0 = threadIdx.x, c1 = threadIdx.x + 256;
  float a0 = 0.f, a1 = 0.f;
  for (int p = beg; p < end; ++p) {
    const u16* er = e_raw + ((size_t)b*E_ + csredg[p])*H_;
    a0 += b2f(er[c0]); a1 += b2f(er[c1]);
  }
  node_raw[(size_t)bi*H_ + c0] = a0;
  node_raw[(size_t)bi*H_ + c1] = a1;
}

// ------- An = bf16(scale1*(A @ node_raw) + shift1*aind[i])  (BN1 fold) -------
__global__ __launch_bounds__(256) void an_kernel(const float* __restrict__ Adj,
    const float* __restrict__ node_raw, const float* __restrict__ scale1,
    const float* __restrict__ shift1, const float* __restrict__ aind, u16* __restrict__ An)
{
  int bi = blockIdx.x;
  int b = bi / J_, i = bi - b*J_;
  __shared__ float Arow[J_];
  if (threadIdx.x < J_) Arow[threadIdx.x] = Adj[i*J_ + threadIdx.x];
  __syncthreads();
  float ai = aind[i];
#pragma unroll
  for (int h = 0; h < 2; ++h) {
    int c = threadIdx.x + h*256;
    const float* nb = node_raw + (size_t)b*J_*H_ + c;
    float acc = 0.f;
    for (int j = 0; j < J_; ++j) acc += Arow[j]*nb[(size_t)j*H_];
    An[(size_t)bi*H_ + c] = f2b(scale1[c]*acc + shift1[c]*ai);
  }
}

// =====================================================================
extern "C" void kernel_launch(void* const* d_in, const int* in_sizes, int n_in,
                              void* d_out, int out_size, void* d_ws, size_t ws_size,
                              hipStream_t stream)
{
  const float* x    = (const float*)d_in[0];
  const int*   ei   = (const int*)d_in[1];
  const float* g1w  = (const float*)d_in[2];
  const float* g1b  = (const float*)d_in[3];
  const float* m1w  = (const float*)d_in[4];
  const float* m1b  = (const float*)d_in[5];
  const float* bn1g = (const float*)d_in[6];
  const float* bn1b = (const float*)d_in[7];
  const float* g2w  = (const float*)d_in[8];
  const float* g2b  = (const float*)d_in[9];
  const float* m2w  = (const float*)d_in[10];
  const float* m2b  = (const float*)d_in[11];
  const float* bn2g = (const float*)d_in[12];
  const float* bn2b = (const float*)d_in[13];
  const float* fcw  = (const float*)d_in[14];
  const float* fcb  = (const float*)d_in[15];

  char* wsp = (char*)d_ws;
  size_t off = 0;
  auto alloc = [&](size_t bytes) -> char* {
    char* p = wsp + off;
    off = (off + bytes + 255) & ~(size_t)255;
    return p;
  };
  float* Adj    = (float*)alloc(J_*J_*4);
  float* aind   = (float*)alloc(J_*4);
  int*   csroff = (int*)alloc((J_+1)*4);
  int*   csredg = (int*)alloc(E_*4);
  float* scale1 = (float*)alloc(H_*4);
  float* shift1 = (float*)alloc(H_*4);
  float* scale2 = (float*)alloc(H_*4);
  float* shift2 = (float*)alloc(H_*4);
  float* crow1  = (float*)alloc(H_*4);
  float* cvec   = (float*)alloc(NOUT_*4);
  double* slots = (double*)alloc((size_t)4*NSLOT*H_*8);   // sum1,sq1,sum2,sq2
  double* sum1 = slots;
  double* sq1  = slots + (size_t)NSLOT*H_;
  double* sum2 = slots + (size_t)2*NSLOT*H_;
  double* sq2  = slots + (size_t)3*NSLOT*H_;
  u16* g1T   = (u16*)alloc((size_t)H_*NIN_*2);
  u16* g2T   = (u16*)alloc((size_t)H_*H_*2);
  u16* W1abT = (u16*)alloc((size_t)2*H_*H_*2);
  u16* W2abT = (u16*)alloc((size_t)2*H_*H_*2);
  u16* WcT   = (u16*)alloc((size_t)H_*H_*2);
  u16* fcT   = (u16*)alloc((size_t)NOUT_*H_*2);
  u16* Ax    = (u16*)alloc((size_t)M_NODE*NIN_*2);
  u16* h     = (u16*)alloc((size_t)M_NODE*H_*2);
  float* hsd  = (float*)alloc((size_t)M_NODE*2*H_*4);   // [1856][1024]: src half | dst half
  float* node_raw = (float*)alloc((size_t)M_NODE*H_*4);
  u16* An    = (u16*)alloc((size_t)M_NODE*H_*2);
  u16* h2    = (u16*)alloc((size_t)M_NODE*H_*2);
  float* h2sd = (float*)alloc((size_t)M_NODE*2*H_*4);
  u16* e_raw = (u16*)alloc((size_t)M_PAD*H_*2);   // raw post-ReLU e (padded rows)
  u16* e2    = (u16*)alloc((size_t)M_PAD*H_*2);   // raw post-ReLU e2 (padded rows)
  if (off > ws_size) return;   // diagnostic: out stays 0

  const int* srcI = ei;
  const int* dstI = ei + E_;
  float* outF = (float*)d_out;   // output is float32

  hipMemsetAsync(slots, 0, (size_t)4*NSLOT*H_*8, stream);
  build_graph<<<1, 256, 0, stream>>>(ei, Adj, aind, csroff, csredg);

  transpose_cv<<<(NIN_*H_+255)/256, 256, 0, stream>>>(g1w, g1T, NIN_, H_);
  transpose_cv<<<(H_*H_+255)/256, 256, 0, stream>>>(g2w, g2T, H_, H_);
  transpose_pair<<<(2*H_*H_+255)/256, 256, 0, stream>>>(m1w, W1abT);
  transpose_pair<<<(2*H_*H_+255)/256, 256, 0, stream>>>(m2w, W2abT);

  ax_kernel<<<M_NODE, 192, 0, stream>>>(Adj, x, Ax);

  // h = relu(Ax @ gcn1_w + b1)
  gemm64<1><<<dim3(M_NODE/64, H_/64), 256, 0, stream>>>(Ax, g1T, M_NODE, H_, NIN_,
      g1b, h, nullptr);
  // hsd = h @ [W1a | W1b]  (N=1024, one GEMM)
  gemm64<0><<<dim3(M_NODE/64, 2*H_/64), 256, 0, stream>>>(h, W1abT, M_NODE, 2*H_, H_,
      nullptr, nullptr, hsd);
  // e_raw = relu(hsd[src,c] + hsd[dst,512+c] + b1) + fused BN1 stats
  edge1_kernel<<<M_EDGE/16, 256, 0, stream>>>(hsd, m1b, srcI, dstI, e_raw, sum1, sq1);
  bn_fin<<<1, 512, 0, stream>>>(sum1, sq1, bn1g, bn1b, scale1, shift1);
  build_wc<<<H_, 256, 0, stream>>>(m2w, m2b, scale1, shift1, WcT, crow1);
  // edge2node on RAW e; BN1 fold applied in an_kernel
  scatter_kernel<<<M_NODE, 256, 0, stream>>>(e_raw, csroff, csredg, node_raw);
  an_kernel<<<M_NODE, 256, 0, stream>>>(Adj, node_raw, scale1, shift1, aind, An);
  // h2 = relu(An @ gcn2_w + b2)
  gemm64<1><<<dim3(M_NODE/64, H_/64), 256, 0, stream>>>(An, g2T, M_NODE, H_, H_,
      g2b, h2, nullptr);
  // h2sd = h2 @ [W2a | W2b]
  gemm64<0><<<dim3(M_NODE/64, 2*H_/64), 256, 0, stream>>>(h2, W2abT, M_NODE, 2*H_, H_,
      nullptr, nullptr, h2sd);
  // e2 = relu(e_raw @ WcT(scaled) + gather(h2sd) + crow1) + fused BN2 stats
  gemm128<2><<<dim3(M_PAD/128, H_/128), 256, 0, stream>>>(e_raw, WcT, H_, H_,
      h2sd, crow1, srcI, dstI, sum2, sq2, e2, nullptr);
  bn_fin<<<1, 512, 0, stream>>>(sum2, sq2, bn2g, bn2b, scale2, shift2);
  build_fc<<<NOUT_, 256, 0, stream>>>(fcw, fcb, scale2, shift2, fcT, cvec);
  // out = e2 @ fcT(scaled) + cvec   (float32 output)
  gemm128<3><<<dim3(M_PAD/128, NOUT_/128), 256, 0, stream>>>(e2, fcT, NOUT_, H_,
      nullptr, cvec, nullptr, nullptr, nullptr, nullptr, nullptr, outF);
}